// Round 1
// baseline (2058.054 us; speedup 1.0000x reference)
//
#include <hip/hip_runtime.h>

#define N_ENT 100000
#define HDIM  200
#define NEDGE 1000000
#define BDIM  512

__device__ __forceinline__ float rrelu_f(float v){
    const float slope = (1.0f/8.0f + 1.0f/3.0f)*0.5f;
    return v >= 0.f ? v : v*slope;
}

// ---- CSR build ----------------------------------------------------------
__global__ void hist_k(const int* __restrict__ dst, int* __restrict__ deg){
    int e = blockIdx.x*blockDim.x + threadIdx.x;
    if (e < NEDGE) atomicAdd(&deg[dst[e]], 1);
}

__global__ void scan_k(const int* __restrict__ deg, int* __restrict__ row_off, int* __restrict__ fill_pos){
    __shared__ int ssum[1024];
    int t = threadIdx.x;
    const int ITEMS = 98;                      // 1024*98 >= 100000
    int base = t*ITEMS;
    int s = 0;
    for (int i=0;i<ITEMS;i++){ int idx=base+i; if (idx<N_ENT) s += deg[idx]; }
    ssum[t] = s;
    __syncthreads();
    for (int off=1; off<1024; off<<=1){
        int v = (t>=off) ? ssum[t-off] : 0;
        __syncthreads();
        ssum[t] += v;
        __syncthreads();
    }
    int run = ssum[t] - s;                     // exclusive prefix
    for (int i=0;i<ITEMS;i++){
        int idx = base+i;
        if (idx<N_ENT){ row_off[idx]=run; fill_pos[idx]=run; run += deg[idx]; }
    }
    if (t==1023) row_off[N_ENT] = run;
}

__global__ void fill_k(const int* __restrict__ src, const int* __restrict__ dst, const int* __restrict__ et,
                       int* __restrict__ fill_pos, int* __restrict__ cs_src, int* __restrict__ cs_et){
    int e = blockIdx.x*blockDim.x + threadIdx.x;
    if (e < NEDGE){
        int p = atomicAdd(&fill_pos[dst[e]], 1);
        cs_src[p] = src[e];
        cs_et[p]  = et[e];
    }
}

// ---- neighbor aggregation: P[n] = (sum_{e: dst=n} X[src_e] + rel[et_e]) / max(deg,1)
__global__ __launch_bounds__(256) void spmm_k(const float* __restrict__ X, const float* __restrict__ rel,
                       const int* __restrict__ cs_src, const int* __restrict__ cs_et,
                       const int* __restrict__ row_off, float* __restrict__ P){
    int wv = (blockIdx.x*256 + threadIdx.x)>>6;   // one wave per dst node
    int lane = threadIdx.x & 63;
    if (wv >= N_ENT) return;
    int beg = row_off[wv], end = row_off[wv+1];
    float a0=0.f,a1=0.f,a2=0.f,a3=0.f;
    for (int e=beg;e<end;e++){
        int s  = cs_src[e];
        int tt = cs_et[e];
        const float* xs = X   + (size_t)s*HDIM;
        const float* rr = rel + (size_t)tt*HDIM;
        a0 += xs[lane]     + rr[lane];
        a1 += xs[64+lane]  + rr[64+lane];
        a2 += xs[128+lane] + rr[128+lane];
        if (lane<8) a3 += xs[192+lane] + rr[192+lane];
    }
    float id = 1.f / fmaxf((float)(end-beg), 1.f);
    float* o = P + (size_t)wv*HDIM;
    o[lane]=a0*id; o[64+lane]=a1*id; o[128+lane]=a2*id;
    if (lane<8) o[192+lane]=a3*id;
}

// ---- gate[n] = sigmoid(gate_theta[n] . gate_w + gate_b)
__global__ __launch_bounds__(256) void gate_k(const float* __restrict__ th, const float* __restrict__ gw,
                       const float* __restrict__ gb, float* __restrict__ gate){
    int wv = (blockIdx.x*256 + threadIdx.x)>>6;
    int lane = threadIdx.x & 63;
    if (wv >= N_ENT) return;
    const float* t = th + (size_t)wv*HDIM;
    float s = t[lane]*gw[lane] + t[64+lane]*gw[64+lane] + t[128+lane]*gw[128+lane];
    if (lane<8) s += t[192+lane]*gw[192+lane];
    #pragma unroll
    for (int off=32; off>=1; off>>=1) s += __shfl_xor(s, off);
    if (lane==0) gate[wv] = 1.f/(1.f + expf(-(s + gb[0])));
}

// ---- repack W[k][c] (200x200) -> Wr[w][k][0..51] = W[k][50w+j] (16B-aligned rows)
__global__ void repack_w_k(const float* __restrict__ W, float* __restrict__ Wr){
    int i = blockIdx.x*blockDim.x + threadIdx.x;
    if (i >= 4*HDIM*52) return;
    int w = i/(HDIM*52); int r = i - w*HDIM*52; int k = r/52; int j = r - k*52;
    Wr[i] = (j<50) ? W[k*HDIM + w*50 + j] : 0.f;
}

// ---- layer GEMM: Out[n] = act(P[n]@Wn + X[n]@Wl); EPI==2 adds gate blend with ent
template<int EPI>
__global__ __launch_bounds__(256) void gemm_layer_k(const float* __restrict__ P, const float* __restrict__ X,
        const float* __restrict__ Wnr, const float* __restrict__ Wlr,
        float* __restrict__ Out, const float* __restrict__ gate, const float* __restrict__ ent){
    __shared__ float smem[2*64*51];
    float* Pl = smem;
    float* Xl = smem + 64*51;
    const int tid  = threadIdx.x;
    const int lane = tid & 63;                    // lane = row within 64-row tile
    const int w    = __builtin_amdgcn_readfirstlane(tid >> 6);  // wave = 50-col group
    const int n0   = blockIdx.x*64;
    float acc[50];
    #pragma unroll
    for (int j=0;j<50;j++) acc[j]=0.f;

    for (int kc=0; kc<HDIM; kc+=50){
        __syncthreads();
        for (int i=tid; i<64*50; i+=256){
            int r = i/50, k = i - r*50;
            int n = n0 + r;
            float pv=0.f, xv=0.f;
            if (n < N_ENT){
                pv = P[(size_t)n*HDIM + kc + k];
                xv = X[(size_t)n*HDIM + kc + k];
            }
            Pl[r*51+k]=pv; Xl[r*51+k]=xv;
        }
        __syncthreads();
        for (int k=0;k<50;k++){
            float p = Pl[lane*51+k];
            float x = Xl[lane*51+k];
            const float4* wn4 = (const float4*)(Wnr + ((size_t)(w*HDIM + kc + k))*52);
            const float4* wl4 = (const float4*)(Wlr + ((size_t)(w*HDIM + kc + k))*52);
            #pragma unroll
            for (int j4=0;j4<12;j4++){
                float4 a = wn4[j4]; float4 b = wl4[j4];
                acc[4*j4+0] += p*a.x + x*b.x;
                acc[4*j4+1] += p*a.y + x*b.y;
                acc[4*j4+2] += p*a.z + x*b.z;
                acc[4*j4+3] += p*a.w + x*b.w;
            }
            float4 a = wn4[12]; float4 b = wl4[12];
            acc[48] += p*a.x + x*b.x;
            acc[49] += p*a.y + x*b.y;
        }
    }
    // epilogue: LDS transpose in two halves for coalesced stores
    float* OutS = smem;  // [64][101]
    for (int half=0; half<2; half++){
        __syncthreads();
        if ((w>>1) == half){
            int wl_ = w & 1;
            #pragma unroll
            for (int j=0;j<50;j++) OutS[lane*101 + wl_*50 + j] = acc[j];
        }
        __syncthreads();
        for (int i=tid; i<64*100; i+=256){
            int r = i/100, c = i - r*100;
            int n = n0 + r;
            if (n < N_ENT){
                int cc = half*100 + c;
                float v = rrelu_f(OutS[r*101+c]);
                if (EPI==2){
                    float g = gate[n];
                    v = g*v + (1.f-g)*ent[(size_t)n*HDIM + cc];
                }
                Out[(size_t)n*HDIM + cc] = v;
            }
        }
    }
}

// ---- BN stats over the 3-channel stack ---------------------------------
__global__ void bn_stats_k(const float* __restrict__ hf, const float* __restrict__ rel,
        const float* __restrict__ freq, const int* __restrict__ s_idx, const int* __restrict__ r_idx,
        float* __restrict__ bnp){
    __shared__ float red[1024];
    int t = threadIdx.x;
    float acc[6]={0,0,0,0,0,0};
    for (int i=t; i<BDIM*HDIM; i+=1024){
        int b = i/HDIM, h = i - b*HDIM;
        float e = hf[(size_t)s_idx[b]*HDIM + h];
        float r = rel[(size_t)r_idx[b]*HDIM + h];
        float f = freq[i];
        acc[0]+=e; acc[1]+=e*e; acc[2]+=r; acc[3]+=r*r; acc[4]+=f; acc[5]+=f*f;
    }
    float tot[6];
    for (int c=0;c<6;c++){
        __syncthreads();
        red[t]=acc[c];
        __syncthreads();
        for (int st=512; st>0; st>>=1){
            if (t<st) red[t]+=red[t+st];
            __syncthreads();
        }
        tot[c]=red[0];
    }
    if (t==0){
        const float inv = 1.f/(float)(BDIM*HDIM);
        for (int c=0;c<3;c++){
            float mean = tot[2*c]*inv;
            float var  = tot[2*c+1]*inv - mean*mean;
            bnp[c]   = mean;
            bnp[3+c] = rsqrtf(var + 1e-5f);
        }
    }
}

// ---- q = conv1x1(relu(BN(stack))) stored transposed qT[h][b] -----------
__global__ void qt_k(const float* __restrict__ hf, const float* __restrict__ rel,
        const float* __restrict__ freq, const int* __restrict__ s_idx, const int* __restrict__ r_idx,
        const float* __restrict__ gamma, const float* __restrict__ beta,
        const float* __restrict__ convw, const float* __restrict__ convb,
        const float* __restrict__ bnp, float* __restrict__ qT){
    int i = blockIdx.x*blockDim.x + threadIdx.x;
    if (i >= BDIM*HDIM) return;
    int b = i/HDIM, h = i - b*HDIM;
    float x0 = hf[(size_t)s_idx[b]*HDIM + h];
    float x1 = rel[(size_t)r_idx[b]*HDIM + h];
    float x2 = freq[i];
    float v0 = fmaxf((x0-bnp[0])*bnp[3]*gamma[0] + beta[0], 0.f);
    float v1 = fmaxf((x1-bnp[1])*bnp[4]*gamma[1] + beta[1], 0.f);
    float v2 = fmaxf((x2-bnp[2])*bnp[5]*gamma[2] + beta[2], 0.f);
    float q = v0*convw[0] + v1*convw[1] + v2*convw[2] + convb[0];
    qT[(size_t)h*BDIM + b] = q;
}

// ---- scores[b][n] = q[b] . hf[n] ---------------------------------------
__global__ __launch_bounds__(256) void scores_k(const float* __restrict__ hf, const float* __restrict__ qT,
        float* __restrict__ out){
    __shared__ float Hs[64*51];
    const int tid  = threadIdx.x;
    const int lane = tid & 63;                    // lane = n within tile
    const int w    = __builtin_amdgcn_readfirstlane(tid >> 6);
    const int n0   = blockIdx.x*64;
    const int b0   = blockIdx.y*256 + w*64;       // 64 b-cols per wave
    float acc[64];
    #pragma unroll
    for (int j=0;j<64;j++) acc[j]=0.f;
    for (int kc=0; kc<HDIM; kc+=50){
        __syncthreads();
        for (int i=tid; i<64*50; i+=256){
            int r=i/50, k=i-r*50;
            int n=n0+r;
            Hs[r*51+k] = (n<N_ENT) ? hf[(size_t)n*HDIM + kc + k] : 0.f;
        }
        __syncthreads();
        for (int k=0;k<50;k++){
            float h = Hs[lane*51+k];
            const float4* q4 = (const float4*)(qT + (size_t)(kc+k)*BDIM + b0);
            #pragma unroll
            for (int j4=0;j4<16;j4++){
                float4 a = q4[j4];
                acc[4*j4+0] += h*a.x;
                acc[4*j4+1] += h*a.y;
                acc[4*j4+2] += h*a.z;
                acc[4*j4+3] += h*a.w;
            }
        }
    }
    int n = n0 + lane;
    if (n < N_ENT){
        #pragma unroll
        for (int j=0;j<64;j++){
            out[(size_t)(b0+j)*N_ENT + n] = acc[j];
        }
    }
}

extern "C" void kernel_launch(void* const* d_in, const int* in_sizes, int n_in,
                              void* d_out, int out_size, void* d_ws, size_t ws_size,
                              hipStream_t stream) {
    const float* ent    = (const float*)d_in[0];
    const float* rel    = (const float*)d_in[1];
    const float* Wn1    = (const float*)d_in[2];
    const float* Wl1    = (const float*)d_in[3];
    const float* Wn2    = (const float*)d_in[4];
    const float* Wl2    = (const float*)d_in[5];
    const float* gtheta = (const float*)d_in[6];
    const float* gw     = (const float*)d_in[7];
    const float* gb     = (const float*)d_in[8];
    const float* gamma  = (const float*)d_in[9];
    const float* beta   = (const float*)d_in[10];
    const float* convw  = (const float*)d_in[11];
    const float* convb  = (const float*)d_in[12];
    const float* freq   = (const float*)d_in[13];
    const int*   src    = (const int*)d_in[14];
    const int*   dst    = (const int*)d_in[15];
    const int*   etype  = (const int*)d_in[16];
    const int*   s_idx  = (const int*)d_in[17];
    const int*   r_idx  = (const int*)d_in[18];
    float* out = (float*)d_out;

    char* ws = (char*)d_ws;
    size_t off = 0;
    auto alloc = [&](size_t bytes)->char*{
        char* p = ws + off;
        off += (bytes + 511) & ~(size_t)511;
        return p;
    };
    int*   deg      = (int*)alloc((size_t)N_ENT*4);
    int*   row_off  = (int*)alloc((size_t)(N_ENT+1)*4);
    int*   fill_pos = (int*)alloc((size_t)N_ENT*4);
    int*   cs_src   = (int*)alloc((size_t)NEDGE*4);
    int*   cs_et    = (int*)alloc((size_t)NEDGE*4);
    float* P        = (float*)alloc((size_t)N_ENT*HDIM*4);   // reused as h_final
    float* h1       = (float*)alloc((size_t)N_ENT*HDIM*4);
    float* gate     = (float*)alloc((size_t)N_ENT*4);
    float* qT       = (float*)alloc((size_t)HDIM*BDIM*4);
    float* bnp      = (float*)alloc(64);
    float* Wr1n     = (float*)alloc((size_t)4*HDIM*52*4);
    float* Wr1l     = (float*)alloc((size_t)4*HDIM*52*4);
    float* Wr2n     = (float*)alloc((size_t)4*HDIM*52*4);
    float* Wr2l     = (float*)alloc((size_t)4*HDIM*52*4);
    float* hf = P;   // h_final aliases P (gemm2 writes only its own rows after reading them)

    hipMemsetAsync(deg, 0, (size_t)N_ENT*4, stream);

    const int EB = (NEDGE + 255)/256;
    hist_k<<<EB,256,0,stream>>>(dst, deg);
    scan_k<<<1,1024,0,stream>>>(deg, row_off, fill_pos);
    fill_k<<<EB,256,0,stream>>>(src, dst, etype, fill_pos, cs_src, cs_et);

    const int RB = (4*HDIM*52 + 255)/256;
    repack_w_k<<<RB,256,0,stream>>>(Wn1, Wr1n);
    repack_w_k<<<RB,256,0,stream>>>(Wl1, Wr1l);
    repack_w_k<<<RB,256,0,stream>>>(Wn2, Wr2n);
    repack_w_k<<<RB,256,0,stream>>>(Wl2, Wr2l);

    const int NWB = N_ENT/4;          // 4 waves per block, 1 node per wave
    const int NTB = (N_ENT + 63)/64;  // 64-row tiles

    // layer 1
    spmm_k<<<NWB,256,0,stream>>>(ent, rel, cs_src, cs_et, row_off, P);
    gemm_layer_k<1><<<NTB,256,0,stream>>>(P, ent, Wr1n, Wr1l, h1, nullptr, nullptr);

    gate_k<<<NWB,256,0,stream>>>(gtheta, gw, gb, gate);

    // layer 2 (+ gate blend fused in epilogue) -> hf
    spmm_k<<<NWB,256,0,stream>>>(h1, rel, cs_src, cs_et, row_off, P);
    gemm_layer_k<2><<<NTB,256,0,stream>>>(P, h1, Wr2n, Wr2l, hf, gate, ent);

    // ConvE head
    bn_stats_k<<<1,1024,0,stream>>>(hf, rel, freq, s_idx, r_idx, bnp);
    qt_k<<<(BDIM*HDIM)/256,256,0,stream>>>(hf, rel, freq, s_idx, r_idx, gamma, beta, convw, convb, bnp, qT);

    // scores
    scores_k<<<dim3(NTB,2),256,0,stream>>>(hf, qT, out);

    (void)in_sizes; (void)n_in; (void)out_size; (void)ws_size;
}

// Round 2
// 1066.766 us; speedup vs baseline: 1.9292x; 1.9292x over previous
//
#include <hip/hip_runtime.h>

#define N_ENT 100000
#define HDIM  200
#define NEDGE 1000000
#define BDIM  512
#define KPAD  416    // [P(200) pad(8) X(200) pad(8)]
#define NPAD  208    // 13 x 16
#define HPAD  224    // 7 x 32 (K for scores)

typedef short  short8v __attribute__((ext_vector_type(8)));
typedef float  float4v __attribute__((ext_vector_type(4)));

__device__ __forceinline__ float rrelu_f(float v){
    const float slope = (1.0f/8.0f + 1.0f/3.0f)*0.5f;
    return v >= 0.f ? v : v*slope;
}
__device__ __forceinline__ unsigned short f2bf(float f){
    unsigned int x = __float_as_uint(f);
    unsigned int r = (x + 0x7fffu + ((x >> 16) & 1u)) >> 16;
    return (unsigned short)r;
}
__device__ __forceinline__ float bf2f(unsigned short u){
    return __uint_as_float(((unsigned int)u) << 16);
}

// ---- CSR build ----------------------------------------------------------
__global__ void hist_k(const int* __restrict__ dst, int* __restrict__ deg){
    int e = blockIdx.x*blockDim.x + threadIdx.x;
    if (e < NEDGE) atomicAdd(&deg[dst[e]], 1);
}

__global__ void scan_k(const int* __restrict__ deg, int* __restrict__ row_off, int* __restrict__ fill_pos){
    __shared__ int ssum[1024];
    int t = threadIdx.x;
    const int ITEMS = 98;
    int base = t*ITEMS;
    int s = 0;
    for (int i=0;i<ITEMS;i++){ int idx=base+i; if (idx<N_ENT) s += deg[idx]; }
    ssum[t] = s;
    __syncthreads();
    for (int off=1; off<1024; off<<=1){
        int v = (t>=off) ? ssum[t-off] : 0;
        __syncthreads();
        ssum[t] += v;
        __syncthreads();
    }
    int run = ssum[t] - s;
    for (int i=0;i<ITEMS;i++){
        int idx = base+i;
        if (idx<N_ENT){ row_off[idx]=run; fill_pos[idx]=run; run += deg[idx]; }
    }
    if (t==1023) row_off[N_ENT] = run;
}

__global__ void fill_k(const int* __restrict__ src, const int* __restrict__ dst, const int* __restrict__ et,
                       int* __restrict__ fill_pos, int* __restrict__ cs_src, int* __restrict__ cs_et){
    int e = blockIdx.x*blockDim.x + threadIdx.x;
    if (e < NEDGE){
        int p = atomicAdd(&fill_pos[dst[e]], 1);
        cs_src[p] = src[e];
        cs_et[p]  = et[e];
    }
}

// ---- prep: ent -> Apack1 X-section (bf16) + zero pads of both Apacks ----
__global__ __launch_bounds__(256) void prep_ent_k(const float* __restrict__ ent,
        unsigned short* __restrict__ A1, unsigned short* __restrict__ A2){
    int w = threadIdx.x >> 6, l = threadIdx.x & 63;
    int n = blockIdx.x*4 + w;
    if (l < 50){
        float4 v = *(const float4*)(ent + (size_t)n*HDIM + 4*l);
        ushort4 o; o.x=f2bf(v.x); o.y=f2bf(v.y); o.z=f2bf(v.z); o.w=f2bf(v.w);
        *(ushort4*)(A1 + (size_t)n*KPAD + NPAD + 4*l) = o;
    }
    if (l < 8){
        A1[(size_t)n*KPAD + 200 + l] = 0; A1[(size_t)n*KPAD + 408 + l] = 0;
        A2[(size_t)n*KPAD + 200 + l] = 0; A2[(size_t)n*KPAD + 408 + l] = 0;
    }
}

__global__ void prep_rel_k(const float* __restrict__ rel, unsigned short* __restrict__ relb){
    int i = blockIdx.x*blockDim.x + threadIdx.x;
    if (i < 460*HDIM) relb[i] = f2bf(rel[i]);
}

// ---- pack [Wn;Wl] (K=416 x N=208, zero-padded) into MFMA B-frag layout ---
// Bpack[((ks*13 + f)*64 + lane)*8 + j] = Wcat[k = ks*32 + (lane>>4)*8 + j][c = f*16 + (lane&15)]
__global__ void pack_w_k(const float* __restrict__ Wn, const float* __restrict__ Wl,
                         unsigned short* __restrict__ Bpack){
    int i = blockIdx.x*blockDim.x + threadIdx.x;
    if (i >= 13*13*64*8) return;
    int j = i & 7, l = (i >> 3) & 63, rest = i >> 9;
    int f = rest % 13, ks = rest / 13;
    int k = ks*32 + ((l >> 4) << 3) + j;
    int c = f*16 + (l & 15);
    float v = 0.f;
    if (c < HDIM){
        if (k < 200)            v = Wn[(size_t)k*HDIM + c];
        else if (k >= 208 && k < 408) v = Wl[(size_t)(k-208)*HDIM + c];
    }
    Bpack[i] = f2bf(v);
}

// ---- neighbor aggregation (bf16 gather, fp32 accum, bf16 out) ------------
// Apack[n][0:200] = (sum_{e:dst=n} Apack[src_e][xoff:xoff+200] + relb[et_e]) / max(deg,1)
__global__ __launch_bounds__(256) void spmm_bf_k(unsigned short* __restrict__ Apack,
        const unsigned short* __restrict__ relb,
        const int* __restrict__ cs_src, const int* __restrict__ cs_et,
        const int* __restrict__ row_off){
    int wv = (blockIdx.x*256 + threadIdx.x) >> 6;
    int l = threadIdx.x & 63;
    int beg = row_off[wv], end = row_off[wv+1];
    if (l >= 50){
        return;  // inactive lanes (wave still progresses)
    }
    float a0=0.f, a1=0.f, a2=0.f, a3=0.f;
    const int el = 4*l;
    for (int e=beg; e<end; e++){
        int s  = cs_src[e];
        int tt = cs_et[e];
        ushort4 xs = *(const ushort4*)(Apack + (size_t)s*KPAD + NPAD + el);
        ushort4 rr = *(const ushort4*)(relb  + (size_t)tt*HDIM + el);
        a0 += bf2f(xs.x) + bf2f(rr.x);
        a1 += bf2f(xs.y) + bf2f(rr.y);
        a2 += bf2f(xs.z) + bf2f(rr.z);
        a3 += bf2f(xs.w) + bf2f(rr.w);
    }
    float id = 1.f / fmaxf((float)(end-beg), 1.f);
    ushort4 o; o.x=f2bf(a0*id); o.y=f2bf(a1*id); o.z=f2bf(a2*id); o.w=f2bf(a3*id);
    *(ushort4*)(Apack + (size_t)wv*KPAD + el) = o;
}

// ---- gate[n] = sigmoid(gate_theta[n] . gate_w + gate_b) ------------------
__global__ __launch_bounds__(256) void gate_k(const float* __restrict__ th, const float* __restrict__ gw,
                       const float* __restrict__ gb, float* __restrict__ gate){
    int wv = (blockIdx.x*256 + threadIdx.x)>>6;
    int lane = threadIdx.x & 63;
    const float* t = th + (size_t)wv*HDIM;
    float s = t[lane]*gw[lane] + t[64+lane]*gw[64+lane] + t[128+lane]*gw[128+lane];
    if (lane<8) s += t[192+lane]*gw[192+lane];
    #pragma unroll
    for (int off=32; off>=1; off>>=1) s += __shfl_xor(s, off);
    if (lane==0) gate[wv] = 1.f/(1.f + expf(-(s + gb[0])));
}

// ---- layer GEMM via MFMA: Out = act([P|X] @ [Wn;Wl]) ---------------------
// EPI==1: rrelu -> bf16 into Apack2 X-section (cols 208..407)
// EPI==2: rrelu -> gate blend with fp32 ent -> bf16 into hfb [N_ENT][HPAD]
template<int EPI>
__global__ __launch_bounds__(256,2) void gemm_layer_mfma_k(
        const unsigned short* __restrict__ Apack,
        const unsigned short* __restrict__ Bpack,
        unsigned short* __restrict__ OutB,
        const float* __restrict__ gate, const float* __restrict__ ent){
    const int tid = threadIdx.x;
    const int l   = tid & 63;
    const int w   = tid >> 6;
    const int n0  = blockIdx.x * 64;
    const int lr  = l & 15;
    const int lg  = l >> 4;
    int na = n0 + w*16 + lr;
    if (na > N_ENT-1) na = N_ENT-1;
    const unsigned short* arow = Apack + (size_t)na*KPAD + lg*8;
    float4v acc[13];
    #pragma unroll
    for (int f=0; f<13; f++) acc[f] = (float4v){0.f,0.f,0.f,0.f};
    for (int ks=0; ks<13; ks++){
        short8v a = *(const short8v*)(arow + ks*32);
        const unsigned short* bp = Bpack + ((size_t)(ks*13)*64 + l)*8;
        #pragma unroll
        for (int f=0; f<13; f++){
            short8v b = *(const short8v*)(bp + (size_t)f*512);
            acc[f] = __builtin_amdgcn_mfma_f32_16x16x32_bf16(a, b, acc[f], 0, 0, 0);
        }
    }
    const int rbase = n0 + w*16 + lg*4;
    #pragma unroll
    for (int f=0; f<13; f++){
        int c = f*16 + lr;
        if (c >= HDIM) continue;
        #pragma unroll
        for (int j=0; j<4; j++){
            int n = rbase + j;
            if (n >= N_ENT) continue;
            float v = rrelu_f(acc[f][j]);
            if (EPI == 2){
                float g = gate[n];
                v = g*v + (1.f-g)*ent[(size_t)n*HDIM + c];
                OutB[(size_t)n*HPAD + c] = f2bf(v);
            } else {
                OutB[(size_t)n*KPAD + NPAD + c] = f2bf(v);
            }
        }
    }
}

// ---- zero hfb pad cols [200,224) ----------------------------------------
__global__ void zero_hfb_pad_k(unsigned short* __restrict__ hfb){
    int i = blockIdx.x*blockDim.x + threadIdx.x;
    if (i >= N_ENT*24) return;
    int n = i / 24, c = 200 + (i - n*24);
    hfb[(size_t)n*HPAD + c] = 0;
}

// ---- BN stats over the 3-channel stack ----------------------------------
__global__ void bn_stats_k(const unsigned short* __restrict__ hfb, const float* __restrict__ rel,
        const float* __restrict__ freq, const int* __restrict__ s_idx, const int* __restrict__ r_idx,
        float* __restrict__ bnp){
    __shared__ float red[1024];
    int t = threadIdx.x;
    float acc[6]={0,0,0,0,0,0};
    for (int i=t; i<BDIM*HDIM; i+=1024){
        int b = i/HDIM, h = i - b*HDIM;
        float e = bf2f(hfb[(size_t)s_idx[b]*HPAD + h]);
        float r = rel[(size_t)r_idx[b]*HDIM + h];
        float f = freq[i];
        acc[0]+=e; acc[1]+=e*e; acc[2]+=r; acc[3]+=r*r; acc[4]+=f; acc[5]+=f*f;
    }
    float tot[6];
    for (int c=0;c<6;c++){
        __syncthreads();
        red[t]=acc[c];
        __syncthreads();
        for (int st=512; st>0; st>>=1){
            if (t<st) red[t]+=red[t+st];
            __syncthreads();
        }
        tot[c]=red[0];
    }
    if (t==0){
        const float inv = 1.f/(float)(BDIM*HDIM);
        for (int c=0;c<3;c++){
            float mean = tot[2*c]*inv;
            float var  = tot[2*c+1]*inv - mean*mean;
            bnp[c]   = mean;
            bnp[3+c] = rsqrtf(var + 1e-5f);
        }
    }
}

// ---- q row-major bf16 [512][HPAD], pads zeroed --------------------------
__global__ void qt_k(const unsigned short* __restrict__ hfb, const float* __restrict__ rel,
        const float* __restrict__ freq, const int* __restrict__ s_idx, const int* __restrict__ r_idx,
        const float* __restrict__ gamma, const float* __restrict__ beta,
        const float* __restrict__ convw, const float* __restrict__ convb,
        const float* __restrict__ bnp, unsigned short* __restrict__ qb){
    int i = blockIdx.x*blockDim.x + threadIdx.x;
    if (i >= BDIM*HPAD) return;
    int b = i/HPAD, h = i - b*HPAD;
    if (h >= HDIM){ qb[i] = 0; return; }
    float x0 = bf2f(hfb[(size_t)s_idx[b]*HPAD + h]);
    float x1 = rel[(size_t)r_idx[b]*HDIM + h];
    float x2 = freq[(size_t)b*HDIM + h];
    float v0 = fmaxf((x0-bnp[0])*bnp[3]*gamma[0] + beta[0], 0.f);
    float v1 = fmaxf((x1-bnp[1])*bnp[4]*gamma[1] + beta[1], 0.f);
    float v2 = fmaxf((x2-bnp[2])*bnp[5]*gamma[2] + beta[2], 0.f);
    float q = v0*convw[0] + v1*convw[1] + v2*convw[2] + convb[0];
    qb[(size_t)b*HPAD + h] = f2bf(q);
}

// ---- scores[b][n] = q[b] . hf[n] via MFMA -------------------------------
__global__ __launch_bounds__(256,2) void scores_mfma_k(
        const unsigned short* __restrict__ hfb,
        const unsigned short* __restrict__ qb,
        float* __restrict__ out){
    const int tid = threadIdx.x;
    const int l   = tid & 63;
    const int w   = tid >> 6;
    const int lr  = l & 15;
    const int lg  = l >> 4;
    const int n0  = blockIdx.x * 32;
    float4v acc[8][2];
    #pragma unroll
    for (int bf=0; bf<8; bf++){ acc[bf][0]=(float4v){0,0,0,0}; acc[bf][1]=(float4v){0,0,0,0}; }
    const unsigned short* h0 = hfb + (size_t)(n0 + lr)*HPAD + lg*8;
    const unsigned short* h1 = hfb + (size_t)(n0 + 16 + lr)*HPAD + lg*8;
    const unsigned short* qrow = qb + (size_t)(w*128 + lr)*HPAD + lg*8;
    for (int ks=0; ks<7; ks++){
        short8v hf0 = *(const short8v*)(h0 + ks*32);
        short8v hf1 = *(const short8v*)(h1 + ks*32);
        #pragma unroll
        for (int bf=0; bf<8; bf++){
            short8v q = *(const short8v*)(qrow + (size_t)bf*16*HPAD + ks*32);
            acc[bf][0] = __builtin_amdgcn_mfma_f32_16x16x32_bf16(q, hf0, acc[bf][0], 0, 0, 0);
            acc[bf][1] = __builtin_amdgcn_mfma_f32_16x16x32_bf16(q, hf1, acc[bf][1], 0, 0, 0);
        }
    }
    #pragma unroll
    for (int bf=0; bf<8; bf++){
        int b = w*128 + bf*16 + lg*4;
        #pragma unroll
        for (int nf=0; nf<2; nf++){
            int n = n0 + nf*16 + lr;
            #pragma unroll
            for (int j=0; j<4; j++){
                out[(size_t)(b+j)*N_ENT + n] = acc[bf][nf][j];
            }
        }
    }
}

extern "C" void kernel_launch(void* const* d_in, const int* in_sizes, int n_in,
                              void* d_out, int out_size, void* d_ws, size_t ws_size,
                              hipStream_t stream) {
    const float* ent    = (const float*)d_in[0];
    const float* rel    = (const float*)d_in[1];
    const float* Wn1    = (const float*)d_in[2];
    const float* Wl1    = (const float*)d_in[3];
    const float* Wn2    = (const float*)d_in[4];
    const float* Wl2    = (const float*)d_in[5];
    const float* gtheta = (const float*)d_in[6];
    const float* gw     = (const float*)d_in[7];
    const float* gb     = (const float*)d_in[8];
    const float* gamma  = (const float*)d_in[9];
    const float* beta   = (const float*)d_in[10];
    const float* convw  = (const float*)d_in[11];
    const float* convb  = (const float*)d_in[12];
    const float* freq   = (const float*)d_in[13];
    const int*   src    = (const int*)d_in[14];
    const int*   dst    = (const int*)d_in[15];
    const int*   etype  = (const int*)d_in[16];
    const int*   s_idx  = (const int*)d_in[17];
    const int*   r_idx  = (const int*)d_in[18];
    float* out = (float*)d_out;

    char* ws = (char*)d_ws;
    size_t off = 0;
    auto alloc = [&](size_t bytes)->char*{
        char* p = ws + off;
        off += (bytes + 511) & ~(size_t)511;
        return p;
    };
    int*   deg      = (int*)alloc((size_t)N_ENT*4);
    int*   row_off  = (int*)alloc((size_t)(N_ENT+1)*4);
    int*   fill_pos = (int*)alloc((size_t)N_ENT*4);
    int*   cs_src   = (int*)alloc((size_t)NEDGE*4);
    int*   cs_et    = (int*)alloc((size_t)NEDGE*4);
    unsigned short* A1   = (unsigned short*)alloc((size_t)N_ENT*KPAD*2);   // [P|ent]; later reused as hfb
    unsigned short* A2   = (unsigned short*)alloc((size_t)N_ENT*KPAD*2);   // [P2|h1]
    unsigned short* relb = (unsigned short*)alloc((size_t)460*HDIM*2);
    unsigned short* Bp1  = (unsigned short*)alloc((size_t)13*13*64*8*2);
    unsigned short* Bp2  = (unsigned short*)alloc((size_t)13*13*64*8*2);
    unsigned short* qb   = (unsigned short*)alloc((size_t)BDIM*HPAD*2);
    float* gate = (float*)alloc((size_t)N_ENT*4);
    float* bnp  = (float*)alloc(64);
    unsigned short* hfb = A1;   // aliases A1 (dead after gemm1)

    hipMemsetAsync(deg, 0, (size_t)N_ENT*4, stream);

    const int EB = (NEDGE + 255)/256;
    hist_k<<<EB,256,0,stream>>>(dst, deg);
    scan_k<<<1,1024,0,stream>>>(deg, row_off, fill_pos);
    fill_k<<<EB,256,0,stream>>>(src, dst, etype, fill_pos, cs_src, cs_et);

    prep_ent_k<<<N_ENT/4,256,0,stream>>>(ent, A1, A2);
    prep_rel_k<<<(460*HDIM+255)/256,256,0,stream>>>(rel, relb);
    pack_w_k<<<(13*13*64*8+255)/256,256,0,stream>>>(Wn1, Wl1, Bp1);
    pack_w_k<<<(13*13*64*8+255)/256,256,0,stream>>>(Wn2, Wl2, Bp2);

    const int NWB = N_ENT/4;            // 4 waves/block, 1 node/wave
    const int GTB = (N_ENT + 63)/64;    // 64-row gemm tiles

    // layer 1: P1 into A1 cols [0,200), then gemm -> h1 into A2 cols [208,408)
    spmm_bf_k<<<NWB,256,0,stream>>>(A1, relb, cs_src, cs_et, row_off);
    gemm_layer_mfma_k<1><<<GTB,256,0,stream>>>(A1, Bp1, A2, nullptr, nullptr);

    zero_hfb_pad_k<<<(N_ENT*24+255)/256,256,0,stream>>>(hfb);
    gate_k<<<NWB,256,0,stream>>>(gtheta, gw, gb, gate);

    // layer 2: P2 into A2 cols [0,200), then gemm (+gate blend) -> hfb
    spmm_bf_k<<<NWB,256,0,stream>>>(A2, relb, cs_src, cs_et, row_off);
    gemm_layer_mfma_k<2><<<GTB,256,0,stream>>>(A2, Bp2, hfb, gate, ent);

    // ConvE head
    bn_stats_k<<<1,1024,0,stream>>>(hfb, rel, freq, s_idx, r_idx, bnp);
    qt_k<<<(BDIM*HPAD+255)/256,256,0,stream>>>(hfb, rel, freq, s_idx, r_idx, gamma, beta, convw, convb, bnp, qb);

    // scores (100000 % 32 == 0 -> no tail)
    scores_mfma_k<<<N_ENT/32,256,0,stream>>>(hfb, qb, out);

    (void)in_sizes; (void)n_in; (void)out_size; (void)ws_size;
}

// Round 3
// 740.376 us; speedup vs baseline: 2.7797x; 1.4408x over previous
//
#include <hip/hip_runtime.h>

#define N_ENT 100000
#define HDIM  200
#define NEDGE 1000000
#define BDIM  512
#define KPAD  416    // [P(200) pad(8) X(200) pad(8)]
#define NPAD  208    // 13 x 16
#define HPAD  224    // 7 x 32 (K for scores)
#define SCAN_TILE 1024
#define SCAN_NB   ((N_ENT + SCAN_TILE - 1)/SCAN_TILE)   // 98
#define BN_NB 32

typedef short  short8v __attribute__((ext_vector_type(8)));
typedef float  float4v __attribute__((ext_vector_type(4)));

__device__ __forceinline__ float rrelu_f(float v){
    const float slope = (1.0f/8.0f + 1.0f/3.0f)*0.5f;
    return v >= 0.f ? v : v*slope;
}
__device__ __forceinline__ unsigned short f2bf(float f){
    unsigned int x = __float_as_uint(f);
    unsigned int r = (x + 0x7fffu + ((x >> 16) & 1u)) >> 16;
    return (unsigned short)r;
}
__device__ __forceinline__ float bf2f(unsigned short u){
    return __uint_as_float(((unsigned int)u) << 16);
}

// ---- CSR build ----------------------------------------------------------
__global__ void hist_k(const int* __restrict__ dst, int* __restrict__ deg){
    int e = blockIdx.x*blockDim.x + threadIdx.x;
    if (e < NEDGE) atomicAdd(&deg[dst[e]], 1);
}

// device-wide exclusive scan of deg[0..N_ENT) in 3 stages
__global__ __launch_bounds__(256) void scan_part_k(const int* __restrict__ deg, int* __restrict__ partial){
    int t = threadIdx.x;
    int base = blockIdx.x*SCAN_TILE + t*4;
    int s = 0;
    if (base + 3 < N_ENT){
        int4 v = *(const int4*)(deg + base);
        s = v.x + v.y + v.z + v.w;
    } else {
        for (int i=0;i<4;i++) if (base+i < N_ENT) s += deg[base+i];
    }
    #pragma unroll
    for (int off=32; off>=1; off>>=1) s += __shfl_xor(s, off);
    __shared__ int ws[4];
    if ((t&63)==0) ws[t>>6] = s;
    __syncthreads();
    if (t==0) partial[blockIdx.x] = ws[0]+ws[1]+ws[2]+ws[3];
}

__global__ void scan_mid_k(int* __restrict__ partial){
    __shared__ int sh[128];
    int t = threadIdx.x;
    int v = (t < SCAN_NB) ? partial[t] : 0;
    sh[t] = v;
    __syncthreads();
    for (int off=1; off<128; off<<=1){
        int u = (t>=off) ? sh[t-off] : 0;
        __syncthreads();
        sh[t] += u;
        __syncthreads();
    }
    if (t < SCAN_NB) partial[t] = sh[t] - v;   // exclusive
}

__global__ __launch_bounds__(256) void scan_fin_k(const int* __restrict__ deg, const int* __restrict__ partial,
        int* __restrict__ row_off, int* __restrict__ fill_pos){
    int t = threadIdx.x;
    int lane = t & 63;
    int base = blockIdx.x*SCAN_TILE + t*4;
    int v0=0,v1=0,v2=0,v3=0;
    if (base+3 < N_ENT){
        int4 v = *(const int4*)(deg + base);
        v0=v.x; v1=v.y; v2=v.z; v3=v.w;
    } else {
        if (base   < N_ENT) v0 = deg[base];
        if (base+1 < N_ENT) v1 = deg[base+1];
        if (base+2 < N_ENT) v2 = deg[base+2];
        if (base+3 < N_ENT) v3 = deg[base+3];
    }
    int s = v0+v1+v2+v3;
    int inc = s;
    #pragma unroll
    for (int off=1; off<64; off<<=1){
        int u = __shfl_up(inc, off);
        if (lane >= off) inc += u;
    }
    __shared__ int wsum[4];
    if (lane==63) wsum[t>>6] = inc;
    __syncthreads();
    int w = t>>6;
    int woff = 0;
    for (int i=0;i<w;i++) woff += wsum[i];
    int exc = partial[blockIdx.x] + woff + inc - s;
    int r0 = exc, r1 = exc+v0, r2 = exc+v0+v1, r3 = exc+v0+v1+v2;
    if (base+3 < N_ENT){
        *(int4*)(row_off+base)  = make_int4(r0,r1,r2,r3);
        *(int4*)(fill_pos+base) = make_int4(r0,r1,r2,r3);
    } else {
        if (base   < N_ENT){ row_off[base]  =r0; fill_pos[base]  =r0; }
        if (base+1 < N_ENT){ row_off[base+1]=r1; fill_pos[base+1]=r1; }
        if (base+2 < N_ENT){ row_off[base+2]=r2; fill_pos[base+2]=r2; }
        if (base+3 < N_ENT){ row_off[base+3]=r3; fill_pos[base+3]=r3; }
    }
    if (blockIdx.x==0 && t==0) row_off[N_ENT] = NEDGE;
}

__global__ void fill_k(const int* __restrict__ src, const int* __restrict__ dst, const int* __restrict__ et,
                       int* __restrict__ fill_pos, int* __restrict__ cs_src, int* __restrict__ cs_et){
    int e = blockIdx.x*blockDim.x + threadIdx.x;
    if (e < NEDGE){
        int p = atomicAdd(&fill_pos[dst[e]], 1);
        cs_src[p] = src[e];
        cs_et[p]  = et[e];
    }
}

// ---- prep: ent -> Apack1 X-section (bf16) + zero pads of both Apacks ----
__global__ __launch_bounds__(256) void prep_ent_k(const float* __restrict__ ent,
        unsigned short* __restrict__ A1, unsigned short* __restrict__ A2){
    int w = threadIdx.x >> 6, l = threadIdx.x & 63;
    int n = blockIdx.x*4 + w;
    if (l < 50){
        float4 v = *(const float4*)(ent + (size_t)n*HDIM + 4*l);
        ushort4 o; o.x=f2bf(v.x); o.y=f2bf(v.y); o.z=f2bf(v.z); o.w=f2bf(v.w);
        *(ushort4*)(A1 + (size_t)n*KPAD + NPAD + 4*l) = o;
    }
    if (l < 8){
        A1[(size_t)n*KPAD + 200 + l] = 0; A1[(size_t)n*KPAD + 408 + l] = 0;
        A2[(size_t)n*KPAD + 200 + l] = 0; A2[(size_t)n*KPAD + 408 + l] = 0;
    }
}

__global__ void prep_rel_k(const float* __restrict__ rel, unsigned short* __restrict__ relb){
    int i = blockIdx.x*blockDim.x + threadIdx.x;
    if (i < 460*HDIM) relb[i] = f2bf(rel[i]);
}

// ---- pack [Wn;Wl] (K=416 x N=208, zero-padded) into MFMA B-frag layout ---
__global__ void pack_w_k(const float* __restrict__ Wn, const float* __restrict__ Wl,
                         unsigned short* __restrict__ Bpack){
    int i = blockIdx.x*blockDim.x + threadIdx.x;
    if (i >= 13*13*64*8) return;
    int j = i & 7, l = (i >> 3) & 63, rest = i >> 9;
    int f = rest % 13, ks = rest / 13;
    int k = ks*32 + ((l >> 4) << 3) + j;
    int c = f*16 + (l & 15);
    float v = 0.f;
    if (c < HDIM){
        if (k < 200)                  v = Wn[(size_t)k*HDIM + c];
        else if (k >= 208 && k < 408) v = Wl[(size_t)(k-208)*HDIM + c];
    }
    Bpack[i] = f2bf(v);
}

// ---- neighbor aggregation (bf16 gather, fp32 accum, bf16 out) ------------
__global__ __launch_bounds__(256) void spmm_bf_k(unsigned short* __restrict__ Apack,
        const unsigned short* __restrict__ relb,
        const int* __restrict__ cs_src, const int* __restrict__ cs_et,
        const int* __restrict__ row_off){
    int wv = (blockIdx.x*256 + threadIdx.x) >> 6;
    int l = threadIdx.x & 63;
    int beg = row_off[wv], end = row_off[wv+1];
    if (l >= 50) return;
    float a0=0.f, a1=0.f, a2=0.f, a3=0.f;
    const int el = 4*l;
    for (int e=beg; e<end; e++){
        int s  = cs_src[e];
        int tt = cs_et[e];
        ushort4 xs = *(const ushort4*)(Apack + (size_t)s*KPAD + NPAD + el);
        ushort4 rr = *(const ushort4*)(relb  + (size_t)tt*HDIM + el);
        a0 += bf2f(xs.x) + bf2f(rr.x);
        a1 += bf2f(xs.y) + bf2f(rr.y);
        a2 += bf2f(xs.z) + bf2f(rr.z);
        a3 += bf2f(xs.w) + bf2f(rr.w);
    }
    float id = 1.f / fmaxf((float)(end-beg), 1.f);
    ushort4 o; o.x=f2bf(a0*id); o.y=f2bf(a1*id); o.z=f2bf(a2*id); o.w=f2bf(a3*id);
    *(ushort4*)(Apack + (size_t)wv*KPAD + el) = o;
}

// ---- gate[n] = sigmoid(gate_theta[n] . gate_w + gate_b) ------------------
__global__ __launch_bounds__(256) void gate_k(const float* __restrict__ th, const float* __restrict__ gw,
                       const float* __restrict__ gb, float* __restrict__ gate){
    int wv = (blockIdx.x*256 + threadIdx.x)>>6;
    int lane = threadIdx.x & 63;
    const float* t = th + (size_t)wv*HDIM;
    float s = t[lane]*gw[lane] + t[64+lane]*gw[64+lane] + t[128+lane]*gw[128+lane];
    if (lane<8) s += t[192+lane]*gw[192+lane];
    #pragma unroll
    for (int off=32; off>=1; off>>=1) s += __shfl_xor(s, off);
    if (lane==0) gate[wv] = 1.f/(1.f + expf(-(s + gb[0])));
}

// ---- layer GEMM via MFMA: Out = act([P|X] @ [Wn;Wl]) ---------------------
template<int EPI>
__global__ __launch_bounds__(256,2) void gemm_layer_mfma_k(
        const unsigned short* __restrict__ Apack,
        const unsigned short* __restrict__ Bpack,
        unsigned short* __restrict__ OutB,
        const float* __restrict__ gate, const float* __restrict__ ent){
    const int tid = threadIdx.x;
    const int l   = tid & 63;
    const int w   = tid >> 6;
    const int n0  = blockIdx.x * 64;
    const int lr  = l & 15;
    const int lg  = l >> 4;
    int na = n0 + w*16 + lr;
    if (na > N_ENT-1) na = N_ENT-1;
    const unsigned short* arow = Apack + (size_t)na*KPAD + lg*8;
    float4v acc[13];
    #pragma unroll
    for (int f=0; f<13; f++) acc[f] = (float4v){0.f,0.f,0.f,0.f};
    for (int ks=0; ks<13; ks++){
        short8v a = *(const short8v*)(arow + ks*32);
        const unsigned short* bp = Bpack + ((size_t)(ks*13)*64 + l)*8;
        #pragma unroll
        for (int f=0; f<13; f++){
            short8v b = *(const short8v*)(bp + (size_t)f*512);
            acc[f] = __builtin_amdgcn_mfma_f32_16x16x32_bf16(a, b, acc[f], 0, 0, 0);
        }
    }
    const int rbase = n0 + w*16 + lg*4;
    #pragma unroll
    for (int f=0; f<13; f++){
        int c = f*16 + lr;
        if (c >= HDIM) continue;
        #pragma unroll
        for (int j=0; j<4; j++){
            int n = rbase + j;
            if (n >= N_ENT) continue;
            float v = rrelu_f(acc[f][j]);
            if (EPI == 2){
                float g = gate[n];
                v = g*v + (1.f-g)*ent[(size_t)n*HDIM + c];
                OutB[(size_t)n*HPAD + c] = f2bf(v);
            } else {
                OutB[(size_t)n*KPAD + NPAD + c] = f2bf(v);
            }
        }
    }
}

// ---- zero hfb pad cols [200,224) ----------------------------------------
__global__ void zero_hfb_pad_k(unsigned short* __restrict__ hfb){
    int i = blockIdx.x*blockDim.x + threadIdx.x;
    if (i >= N_ENT*24) return;
    int n = i / 24, c = 200 + (i - n*24);
    hfb[(size_t)n*HPAD + c] = 0;
}

// ---- BN stats: stage 1 (32-block deterministic partial sums) ------------
__global__ __launch_bounds__(256) void bn_part_k(const unsigned short* __restrict__ hfb,
        const float* __restrict__ rel, const float* __restrict__ freq,
        const int* __restrict__ s_idx, const int* __restrict__ r_idx,
        float* __restrict__ bnpart){
    int t = threadIdx.x;
    float acc[6] = {0,0,0,0,0,0};
    for (int i = blockIdx.x*256 + t; i < BDIM*HDIM; i += BN_NB*256){
        int b = i/HDIM, h = i - b*HDIM;
        float e = bf2f(hfb[(size_t)s_idx[b]*HPAD + h]);
        float r = rel[(size_t)r_idx[b]*HDIM + h];
        float f = freq[i];
        acc[0]+=e; acc[1]+=e*e; acc[2]+=r; acc[3]+=r*r; acc[4]+=f; acc[5]+=f*f;
    }
    __shared__ float red[4][6];
    #pragma unroll
    for (int c=0;c<6;c++){
        float s = acc[c];
        #pragma unroll
        for (int off=32; off>=1; off>>=1) s += __shfl_xor(s, off);
        if ((t&63)==0) red[t>>6][c] = s;
    }
    __syncthreads();
    if (t==0){
        #pragma unroll
        for (int c=0;c<6;c++)
            bnpart[blockIdx.x*6+c] = red[0][c]+red[1][c]+red[2][c]+red[3][c];
    }
}

__global__ void bn_fin_k(const float* __restrict__ bnpart, float* __restrict__ bnp){
    int t = threadIdx.x;
    if (t < 3){
        float s=0.f, q=0.f;
        for (int b=0;b<BN_NB;b++){ s += bnpart[b*6+2*t]; q += bnpart[b*6+2*t+1]; }
        const float inv = 1.f/(float)(BDIM*HDIM);
        float mean = s*inv;
        float var  = q*inv - mean*mean;
        bnp[t]   = mean;
        bnp[3+t] = rsqrtf(var + 1e-5f);
    }
}

// ---- q row-major bf16 [512][HPAD], pads zeroed --------------------------
__global__ void qt_k(const unsigned short* __restrict__ hfb, const float* __restrict__ rel,
        const float* __restrict__ freq, const int* __restrict__ s_idx, const int* __restrict__ r_idx,
        const float* __restrict__ gamma, const float* __restrict__ beta,
        const float* __restrict__ convw, const float* __restrict__ convb,
        const float* __restrict__ bnp, unsigned short* __restrict__ qb){
    int i = blockIdx.x*blockDim.x + threadIdx.x;
    if (i >= BDIM*HPAD) return;
    int b = i/HPAD, h = i - b*HPAD;
    if (h >= HDIM){ qb[i] = 0; return; }
    float x0 = bf2f(hfb[(size_t)s_idx[b]*HPAD + h]);
    float x1 = rel[(size_t)r_idx[b]*HDIM + h];
    float x2 = freq[(size_t)b*HDIM + h];
    float v0 = fmaxf((x0-bnp[0])*bnp[3]*gamma[0] + beta[0], 0.f);
    float v1 = fmaxf((x1-bnp[1])*bnp[4]*gamma[1] + beta[1], 0.f);
    float v2 = fmaxf((x2-bnp[2])*bnp[5]*gamma[2] + beta[2], 0.f);
    float q = v0*convw[0] + v1*convw[1] + v2*convw[2] + convb[0];
    qb[(size_t)b*HPAD + h] = f2bf(q);
}

// ---- scores[b][n] = q[b] . hf[n] via MFMA -------------------------------
__global__ __launch_bounds__(256,2) void scores_mfma_k(
        const unsigned short* __restrict__ hfb,
        const unsigned short* __restrict__ qb,
        float* __restrict__ out){
    const int tid = threadIdx.x;
    const int l   = tid & 63;
    const int w   = tid >> 6;
    const int lr  = l & 15;
    const int lg  = l >> 4;
    const int n0  = blockIdx.x * 32;
    float4v acc[8][2];
    #pragma unroll
    for (int bf=0; bf<8; bf++){ acc[bf][0]=(float4v){0,0,0,0}; acc[bf][1]=(float4v){0,0,0,0}; }
    const unsigned short* h0 = hfb + (size_t)(n0 + lr)*HPAD + lg*8;
    const unsigned short* h1 = hfb + (size_t)(n0 + 16 + lr)*HPAD + lg*8;
    const unsigned short* qrow = qb + (size_t)(w*128 + lr)*HPAD + lg*8;
    for (int ks=0; ks<7; ks++){
        short8v hf0 = *(const short8v*)(h0 + ks*32);
        short8v hf1 = *(const short8v*)(h1 + ks*32);
        #pragma unroll
        for (int bf=0; bf<8; bf++){
            short8v q = *(const short8v*)(qrow + (size_t)bf*16*HPAD + ks*32);
            acc[bf][0] = __builtin_amdgcn_mfma_f32_16x16x32_bf16(q, hf0, acc[bf][0], 0, 0, 0);
            acc[bf][1] = __builtin_amdgcn_mfma_f32_16x16x32_bf16(q, hf1, acc[bf][1], 0, 0, 0);
        }
    }
    #pragma unroll
    for (int bf=0; bf<8; bf++){
        int b = w*128 + bf*16 + lg*4;
        #pragma unroll
        for (int nf=0; nf<2; nf++){
            int n = n0 + nf*16 + lr;
            #pragma unroll
            for (int j=0; j<4; j++){
                out[(size_t)(b+j)*N_ENT + n] = acc[bf][nf][j];
            }
        }
    }
}

extern "C" void kernel_launch(void* const* d_in, const int* in_sizes, int n_in,
                              void* d_out, int out_size, void* d_ws, size_t ws_size,
                              hipStream_t stream) {
    const float* ent    = (const float*)d_in[0];
    const float* rel    = (const float*)d_in[1];
    const float* Wn1    = (const float*)d_in[2];
    const float* Wl1    = (const float*)d_in[3];
    const float* Wn2    = (const float*)d_in[4];
    const float* Wl2    = (const float*)d_in[5];
    const float* gtheta = (const float*)d_in[6];
    const float* gw     = (const float*)d_in[7];
    const float* gb     = (const float*)d_in[8];
    const float* gamma  = (const float*)d_in[9];
    const float* beta   = (const float*)d_in[10];
    const float* convw  = (const float*)d_in[11];
    const float* convb  = (const float*)d_in[12];
    const float* freq   = (const float*)d_in[13];
    const int*   src    = (const int*)d_in[14];
    const int*   dst    = (const int*)d_in[15];
    const int*   etype  = (const int*)d_in[16];
    const int*   s_idx  = (const int*)d_in[17];
    const int*   r_idx  = (const int*)d_in[18];
    float* out = (float*)d_out;

    char* ws = (char*)d_ws;
    size_t off = 0;
    auto alloc = [&](size_t bytes)->char*{
        char* p = ws + off;
        off += (bytes + 511) & ~(size_t)511;
        return p;
    };
    int*   deg      = (int*)alloc((size_t)N_ENT*4);
    int*   row_off  = (int*)alloc((size_t)(N_ENT+1)*4);
    int*   fill_pos = (int*)alloc((size_t)N_ENT*4);
    int*   partial  = (int*)alloc((size_t)SCAN_NB*4);
    int*   cs_src   = (int*)alloc((size_t)NEDGE*4);
    int*   cs_et    = (int*)alloc((size_t)NEDGE*4);
    unsigned short* A1   = (unsigned short*)alloc((size_t)N_ENT*KPAD*2);
    unsigned short* A2   = (unsigned short*)alloc((size_t)N_ENT*KPAD*2);
    unsigned short* relb = (unsigned short*)alloc((size_t)460*HDIM*2);
    unsigned short* Bp1  = (unsigned short*)alloc((size_t)13*13*64*8*2);
    unsigned short* Bp2  = (unsigned short*)alloc((size_t)13*13*64*8*2);
    unsigned short* qb   = (unsigned short*)alloc((size_t)BDIM*HPAD*2);
    float* gate   = (float*)alloc((size_t)N_ENT*4);
    float* bnpart = (float*)alloc((size_t)BN_NB*6*4);
    float* bnp    = (float*)alloc(64);
    unsigned short* hfb = A1;   // aliases A1 (dead after gemm1)

    hipMemsetAsync(deg, 0, (size_t)N_ENT*4, stream);

    const int EB = (NEDGE + 255)/256;
    hist_k<<<EB,256,0,stream>>>(dst, deg);
    scan_part_k<<<SCAN_NB,256,0,stream>>>(deg, partial);
    scan_mid_k<<<1,128,0,stream>>>(partial);
    scan_fin_k<<<SCAN_NB,256,0,stream>>>(deg, partial, row_off, fill_pos);
    fill_k<<<EB,256,0,stream>>>(src, dst, etype, fill_pos, cs_src, cs_et);

    prep_ent_k<<<N_ENT/4,256,0,stream>>>(ent, A1, A2);
    prep_rel_k<<<(460*HDIM+255)/256,256,0,stream>>>(rel, relb);
    pack_w_k<<<(13*13*64*8+255)/256,256,0,stream>>>(Wn1, Wl1, Bp1);
    pack_w_k<<<(13*13*64*8+255)/256,256,0,stream>>>(Wn2, Wl2, Bp2);

    const int NWB = N_ENT/4;            // 4 waves/block, 1 node/wave
    const int GTB = (N_ENT + 63)/64;    // 64-row gemm tiles

    // layer 1
    spmm_bf_k<<<NWB,256,0,stream>>>(A1, relb, cs_src, cs_et, row_off);
    gemm_layer_mfma_k<1><<<GTB,256,0,stream>>>(A1, Bp1, A2, nullptr, nullptr);

    zero_hfb_pad_k<<<(N_ENT*24+255)/256,256,0,stream>>>(hfb);
    gate_k<<<NWB,256,0,stream>>>(gtheta, gw, gb, gate);

    // layer 2 (+ gate blend)
    spmm_bf_k<<<NWB,256,0,stream>>>(A2, relb, cs_src, cs_et, row_off);
    gemm_layer_mfma_k<2><<<GTB,256,0,stream>>>(A2, Bp2, hfb, gate, ent);

    // ConvE head
    bn_part_k<<<BN_NB,256,0,stream>>>(hfb, rel, freq, s_idx, r_idx, bnpart);
    bn_fin_k<<<1,64,0,stream>>>(bnpart, bnp);
    qt_k<<<(BDIM*HPAD+255)/256,256,0,stream>>>(hfb, rel, freq, s_idx, r_idx, gamma, beta, convw, convb, bnp, qb);

    // scores
    scores_mfma_k<<<N_ENT/32,256,0,stream>>>(hfb, qb, out);

    (void)in_sizes; (void)n_in; (void)out_size; (void)ws_size;
}

// Round 4
// 703.986 us; speedup vs baseline: 2.9234x; 1.0517x over previous
//
#include <hip/hip_runtime.h>

#define N_ENT 100000
#define HDIM  200
#define NEDGE 1000000
#define BDIM  512
#define KPAD  416    // [P(200) pad(8) X(200) pad(8)]
#define NPAD  208    // 13 x 16
#define HPAD  224    // 7 x 32 (K for scores)
#define SCAN_TILE 1024
#define SCAN_NB   ((N_ENT + SCAN_TILE - 1)/SCAN_TILE)   // 98
#define BN_NB 32

typedef short  short8v __attribute__((ext_vector_type(8)));
typedef float  float4v __attribute__((ext_vector_type(4)));

__device__ __forceinline__ float rrelu_f(float v){
    const float slope = (1.0f/8.0f + 1.0f/3.0f)*0.5f;
    return v >= 0.f ? v : v*slope;
}
__device__ __forceinline__ unsigned short f2bf(float f){
    unsigned int x = __float_as_uint(f);
    unsigned int r = (x + 0x7fffu + ((x >> 16) & 1u)) >> 16;
    return (unsigned short)r;
}
__device__ __forceinline__ float bf2f(unsigned short u){
    return __uint_as_float(((unsigned int)u) << 16);
}

// ---- CSR build ----------------------------------------------------------
__global__ void hist_k(const int* __restrict__ dst, int* __restrict__ deg){
    int e = blockIdx.x*blockDim.x + threadIdx.x;
    if (e < NEDGE) atomicAdd(&deg[dst[e]], 1);
}

__global__ __launch_bounds__(256) void scan_part_k(const int* __restrict__ deg, int* __restrict__ partial){
    int t = threadIdx.x;
    int base = blockIdx.x*SCAN_TILE + t*4;
    int s = 0;
    if (base + 3 < N_ENT){
        int4 v = *(const int4*)(deg + base);
        s = v.x + v.y + v.z + v.w;
    } else {
        for (int i=0;i<4;i++) if (base+i < N_ENT) s += deg[base+i];
    }
    #pragma unroll
    for (int off=32; off>=1; off>>=1) s += __shfl_xor(s, off);
    __shared__ int ws[4];
    if ((t&63)==0) ws[t>>6] = s;
    __syncthreads();
    if (t==0) partial[blockIdx.x] = ws[0]+ws[1]+ws[2]+ws[3];
}

__global__ void scan_mid_k(int* __restrict__ partial){
    __shared__ int sh[128];
    int t = threadIdx.x;
    int v = (t < SCAN_NB) ? partial[t] : 0;
    sh[t] = v;
    __syncthreads();
    for (int off=1; off<128; off<<=1){
        int u = (t>=off) ? sh[t-off] : 0;
        __syncthreads();
        sh[t] += u;
        __syncthreads();
    }
    if (t < SCAN_NB) partial[t] = sh[t] - v;   // exclusive
}

__global__ __launch_bounds__(256) void scan_fin_k(const int* __restrict__ deg, const int* __restrict__ partial,
        int* __restrict__ row_off, int* __restrict__ fill_pos){
    int t = threadIdx.x;
    int lane = t & 63;
    int base = blockIdx.x*SCAN_TILE + t*4;
    int v0=0,v1=0,v2=0,v3=0;
    if (base+3 < N_ENT){
        int4 v = *(const int4*)(deg + base);
        v0=v.x; v1=v.y; v2=v.z; v3=v.w;
    } else {
        if (base   < N_ENT) v0 = deg[base];
        if (base+1 < N_ENT) v1 = deg[base+1];
        if (base+2 < N_ENT) v2 = deg[base+2];
        if (base+3 < N_ENT) v3 = deg[base+3];
    }
    int s = v0+v1+v2+v3;
    int inc = s;
    #pragma unroll
    for (int off=1; off<64; off<<=1){
        int u = __shfl_up(inc, off);
        if (lane >= off) inc += u;
    }
    __shared__ int wsum[4];
    if (lane==63) wsum[t>>6] = inc;
    __syncthreads();
    int w = t>>6;
    int woff = 0;
    for (int i=0;i<w;i++) woff += wsum[i];
    int exc = partial[blockIdx.x] + woff + inc - s;
    int r0 = exc, r1 = exc+v0, r2 = exc+v0+v1, r3 = exc+v0+v1+v2;
    if (base+3 < N_ENT){
        *(int4*)(row_off+base)  = make_int4(r0,r1,r2,r3);
        *(int4*)(fill_pos+base) = make_int4(r0,r1,r2,r3);
    } else {
        if (base   < N_ENT){ row_off[base]  =r0; fill_pos[base]  =r0; }
        if (base+1 < N_ENT){ row_off[base+1]=r1; fill_pos[base+1]=r1; }
        if (base+2 < N_ENT){ row_off[base+2]=r2; fill_pos[base+2]=r2; }
        if (base+3 < N_ENT){ row_off[base+3]=r3; fill_pos[base+3]=r3; }
    }
    if (blockIdx.x==0 && t==0) row_off[N_ENT] = NEDGE;
}

__global__ void fill_k(const int* __restrict__ src, const int* __restrict__ dst, const int* __restrict__ et,
                       int* __restrict__ fill_pos, int2* __restrict__ cs){
    int e = blockIdx.x*blockDim.x + threadIdx.x;
    if (e < NEDGE){
        int p = atomicAdd(&fill_pos[dst[e]], 1);
        cs[p] = make_int2(src[e], et[e]);
    }
}

// ---- prep: ent -> A1 X-section + entb (bf16) + zero pads ----------------
__global__ __launch_bounds__(256) void prep_ent_k(const float* __restrict__ ent,
        unsigned short* __restrict__ A1, unsigned short* __restrict__ A2,
        unsigned short* __restrict__ entb){
    int w = threadIdx.x >> 6, l = threadIdx.x & 63;
    int n = blockIdx.x*4 + w;
    if (l < 50){
        float4 v = *(const float4*)(ent + (size_t)n*HDIM + 4*l);
        ushort4 o; o.x=f2bf(v.x); o.y=f2bf(v.y); o.z=f2bf(v.z); o.w=f2bf(v.w);
        *(ushort4*)(A1 + (size_t)n*KPAD + NPAD + 4*l) = o;
        *(ushort4*)(entb + (size_t)n*HDIM + 4*l) = o;
    }
    if (l < 8){
        A1[(size_t)n*KPAD + 200 + l] = 0; A1[(size_t)n*KPAD + 408 + l] = 0;
        A2[(size_t)n*KPAD + 200 + l] = 0; A2[(size_t)n*KPAD + 408 + l] = 0;
    }
}

__global__ void prep_rel_k(const float* __restrict__ rel, unsigned short* __restrict__ relb){
    int i = blockIdx.x*blockDim.x + threadIdx.x;
    if (i < 460*HDIM) relb[i] = f2bf(rel[i]);
}

// ---- pack [Wn;Wl] (K=416 x N=208, zero-padded) into MFMA B-frag layout ---
__global__ void pack_w_k(const float* __restrict__ Wn, const float* __restrict__ Wl,
                         unsigned short* __restrict__ Bpack){
    int i = blockIdx.x*blockDim.x + threadIdx.x;
    if (i >= 13*13*64*8) return;
    int j = i & 7, l = (i >> 3) & 63, rest = i >> 9;
    int f = rest % 13, ks = rest / 13;
    int k = ks*32 + ((l >> 4) << 3) + j;
    int c = f*16 + (l & 15);
    float v = 0.f;
    if (c < HDIM){
        if (k < 200)                  v = Wn[(size_t)k*HDIM + c];
        else if (k >= 208 && k < 408) v = Wl[(size_t)(k-208)*HDIM + c];
    }
    Bpack[i] = f2bf(v);
}

// ---- neighbor aggregation (bf16 gather, fp32 accum, bf16 out) ------------
__global__ __launch_bounds__(256) void spmm_bf_k(unsigned short* __restrict__ Apack,
        const unsigned short* __restrict__ relb,
        const int2* __restrict__ cs,
        const int* __restrict__ row_off){
    int wv = (blockIdx.x*256 + threadIdx.x) >> 6;
    int l = threadIdx.x & 63;
    int beg = row_off[wv], end = row_off[wv+1];
    if (l >= 50) return;
    float a0=0.f, a1=0.f, a2=0.f, a3=0.f;
    const int el = 4*l;
    for (int e=beg; e<end; e++){
        int2 se = cs[e];
        ushort4 xs = *(const ushort4*)(Apack + (size_t)se.x*KPAD + NPAD + el);
        ushort4 rr = *(const ushort4*)(relb  + (size_t)se.y*HDIM + el);
        a0 += bf2f(xs.x) + bf2f(rr.x);
        a1 += bf2f(xs.y) + bf2f(rr.y);
        a2 += bf2f(xs.z) + bf2f(rr.z);
        a3 += bf2f(xs.w) + bf2f(rr.w);
    }
    float id = 1.f / fmaxf((float)(end-beg), 1.f);
    ushort4 o; o.x=f2bf(a0*id); o.y=f2bf(a1*id); o.z=f2bf(a2*id); o.w=f2bf(a3*id);
    *(ushort4*)(Apack + (size_t)wv*KPAD + el) = o;
}

// ---- gate[n] = sigmoid(gate_theta[n] . gate_w + gate_b) ------------------
__global__ __launch_bounds__(256) void gate_k(const float* __restrict__ th, const float* __restrict__ gw,
                       const float* __restrict__ gb, float* __restrict__ gate){
    int wv = (blockIdx.x*256 + threadIdx.x)>>6;
    int lane = threadIdx.x & 63;
    const float* t = th + (size_t)wv*HDIM;
    float s = t[lane]*gw[lane] + t[64+lane]*gw[64+lane] + t[128+lane]*gw[128+lane];
    if (lane<8) s += t[192+lane]*gw[192+lane];
    #pragma unroll
    for (int off=32; off>=1; off>>=1) s += __shfl_xor(s, off);
    if (lane==0) gate[wv] = 1.f/(1.f + expf(-(s + gb[0])));
}

// ---- layer GEMM via MFMA: Out = act([P|X] @ [Wn;Wl]) ---------------------
// 128 rows/block, 32 rows/wave (2x16 frags). Epilogue through LDS, 16B stores.
template<int EPI>
__global__ __launch_bounds__(256,2) void gemm_layer_mfma_k(
        const unsigned short* __restrict__ Apack,
        const unsigned short* __restrict__ Bpack,
        unsigned short* __restrict__ OutB,
        const float* __restrict__ gate, const unsigned short* __restrict__ entb){
    __shared__ unsigned short OutS[128*208];
    const int tid = threadIdx.x;
    const int l   = tid & 63;
    const int w   = tid >> 6;
    const int n0  = blockIdx.x * 128;
    const int lr  = l & 15;
    const int lg  = l >> 4;
    int r0 = n0 + w*32 + lr;
    int r1 = r0 + 16;
    int c0 = r0 < N_ENT ? r0 : N_ENT-1;
    int c1 = r1 < N_ENT ? r1 : N_ENT-1;
    const unsigned short* ar0 = Apack + (size_t)c0*KPAD + lg*8;
    const unsigned short* ar1 = Apack + (size_t)c1*KPAD + lg*8;
    float4v acc[2][13];
    #pragma unroll
    for (int f=0; f<13; f++){
        acc[0][f] = (float4v){0.f,0.f,0.f,0.f};
        acc[1][f] = (float4v){0.f,0.f,0.f,0.f};
    }
    short8v a0 = *(const short8v*)(ar0);
    short8v a1 = *(const short8v*)(ar1);
    for (int ks=0; ks<13; ks++){
        short8v na0 = a0, na1 = a1;
        if (ks < 12){
            na0 = *(const short8v*)(ar0 + (ks+1)*32);
            na1 = *(const short8v*)(ar1 + (ks+1)*32);
        }
        const unsigned short* bp = Bpack + ((size_t)(ks*13)*64 + l)*8;
        #pragma unroll
        for (int f=0; f<13; f++){
            short8v b = *(const short8v*)(bp + (size_t)f*512);
            acc[0][f] = __builtin_amdgcn_mfma_f32_16x16x32_bf16(a0, b, acc[0][f], 0, 0, 0);
            acc[1][f] = __builtin_amdgcn_mfma_f32_16x16x32_bf16(a1, b, acc[1][f], 0, 0, 0);
        }
        a0 = na0; a1 = na1;
    }
    // acc -> LDS (rrelu applied), rows w*32+{lg*4+j, 16+lg*4+j}, col f*16+lr
    #pragma unroll
    for (int f=0; f<13; f++){
        int c = f*16 + lr;
        if (c < HDIM){
            #pragma unroll
            for (int j=0; j<4; j++){
                OutS[(w*32 + lg*4 + j)*208 + c]      = f2bf(rrelu_f(acc[0][f][j]));
                OutS[(w*32 + 16 + lg*4 + j)*208 + c] = f2bf(rrelu_f(acc[1][f][j]));
            }
        }
    }
    __syncthreads();
    // coalesced 16B stores; EPI2 blends with gate/entb
    for (int i = tid; i < 128*25; i += 256){
        int r = i/25, seg = i - r*25;
        int n = n0 + r;
        if (n >= N_ENT) continue;
        short8v v = *(const short8v*)(&OutS[r*208 + seg*8]);
        if (EPI == 2){
            float g = gate[n];
            short8v eb = *(const short8v*)(entb + (size_t)n*HDIM + seg*8);
            short8v o;
            #pragma unroll
            for (int j=0; j<8; j++){
                float x = g*bf2f((unsigned short)v[j]) + (1.f-g)*bf2f((unsigned short)eb[j]);
                o[j] = (short)f2bf(x);
            }
            *(short8v*)(OutB + (size_t)n*HPAD + seg*8) = o;
        } else {
            *(short8v*)(OutB + (size_t)n*KPAD + NPAD + seg*8) = v;
        }
    }
}

// ---- zero hfb pad cols [200,224) ----------------------------------------
__global__ void zero_hfb_pad_k(unsigned short* __restrict__ hfb){
    int i = blockIdx.x*blockDim.x + threadIdx.x;
    if (i >= N_ENT*24) return;
    int n = i / 24, c = 200 + (i - n*24);
    hfb[(size_t)n*HPAD + c] = 0;
}

// ---- BN stats: stage 1 (32-block deterministic partial sums) ------------
__global__ __launch_bounds__(256) void bn_part_k(const unsigned short* __restrict__ hfb,
        const float* __restrict__ rel, const float* __restrict__ freq,
        const int* __restrict__ s_idx, const int* __restrict__ r_idx,
        float* __restrict__ bnpart){
    int t = threadIdx.x;
    float acc[6] = {0,0,0,0,0,0};
    for (int i = blockIdx.x*256 + t; i < BDIM*HDIM; i += BN_NB*256){
        int b = i/HDIM, h = i - b*HDIM;
        float e = bf2f(hfb[(size_t)s_idx[b]*HPAD + h]);
        float r = rel[(size_t)r_idx[b]*HDIM + h];
        float f = freq[i];
        acc[0]+=e; acc[1]+=e*e; acc[2]+=r; acc[3]+=r*r; acc[4]+=f; acc[5]+=f*f;
    }
    __shared__ float red[4][6];
    #pragma unroll
    for (int c=0;c<6;c++){
        float s = acc[c];
        #pragma unroll
        for (int off=32; off>=1; off>>=1) s += __shfl_xor(s, off);
        if ((t&63)==0) red[t>>6][c] = s;
    }
    __syncthreads();
    if (t==0){
        #pragma unroll
        for (int c=0;c<6;c++)
            bnpart[blockIdx.x*6+c] = red[0][c]+red[1][c]+red[2][c]+red[3][c];
    }
}

__global__ void bn_fin_k(const float* __restrict__ bnpart, float* __restrict__ bnp){
    int t = threadIdx.x;
    if (t < 3){
        float s=0.f, q=0.f;
        for (int b=0;b<BN_NB;b++){ s += bnpart[b*6+2*t]; q += bnpart[b*6+2*t+1]; }
        const float inv = 1.f/(float)(BDIM*HDIM);
        float mean = s*inv;
        float var  = q*inv - mean*mean;
        bnp[t]   = mean;
        bnp[3+t] = rsqrtf(var + 1e-5f);
    }
}

// ---- q row-major bf16 [512][HPAD], pads zeroed --------------------------
__global__ void qt_k(const unsigned short* __restrict__ hfb, const float* __restrict__ rel,
        const float* __restrict__ freq, const int* __restrict__ s_idx, const int* __restrict__ r_idx,
        const float* __restrict__ gamma, const float* __restrict__ beta,
        const float* __restrict__ convw, const float* __restrict__ convb,
        const float* __restrict__ bnp, unsigned short* __restrict__ qb){
    int i = blockIdx.x*blockDim.x + threadIdx.x;
    if (i >= BDIM*HPAD) return;
    int b = i/HPAD, h = i - b*HPAD;
    if (h >= HDIM){ qb[i] = 0; return; }
    float x0 = bf2f(hfb[(size_t)s_idx[b]*HPAD + h]);
    float x1 = rel[(size_t)r_idx[b]*HDIM + h];
    float x2 = freq[(size_t)b*HDIM + h];
    float v0 = fmaxf((x0-bnp[0])*bnp[3]*gamma[0] + beta[0], 0.f);
    float v1 = fmaxf((x1-bnp[1])*bnp[4]*gamma[1] + beta[1], 0.f);
    float v2 = fmaxf((x2-bnp[2])*bnp[5]*gamma[2] + beta[2], 0.f);
    float q = v0*convw[0] + v1*convw[1] + v2*convw[2] + convb[0];
    qb[(size_t)b*HPAD + h] = f2bf(q);
}

// ---- scores[b][n] = q[b] . hf[n] via MFMA, 64-row n-tiles ---------------
__global__ __launch_bounds__(256,2) void scores_mfma_k(
        const unsigned short* __restrict__ hfb,
        const unsigned short* __restrict__ qb,
        float* __restrict__ out){
    const int tid = threadIdx.x;
    const int l   = tid & 63;
    const int w   = tid >> 6;
    const int lr  = l & 15;
    const int lg  = l >> 4;
    const int n0  = blockIdx.x * 64;
    float4v acc[8][4];
    #pragma unroll
    for (int bf=0; bf<8; bf++)
        #pragma unroll
        for (int nf=0; nf<4; nf++) acc[bf][nf] = (float4v){0,0,0,0};
    const unsigned short* hptr[4];
    #pragma unroll
    for (int nf=0; nf<4; nf++){
        int n = n0 + nf*16 + lr;
        if (n >= N_ENT) n = N_ENT-1;
        hptr[nf] = hfb + (size_t)n*HPAD + lg*8;
    }
    const unsigned short* qrow = qb + (size_t)(w*128 + lr)*HPAD + lg*8;
    for (int ks=0; ks<7; ks++){
        short8v hv[4];
        #pragma unroll
        for (int nf=0; nf<4; nf++) hv[nf] = *(const short8v*)(hptr[nf] + ks*32);
        #pragma unroll
        for (int bf=0; bf<8; bf++){
            short8v q = *(const short8v*)(qrow + (size_t)bf*16*HPAD + ks*32);
            #pragma unroll
            for (int nf=0; nf<4; nf++)
                acc[bf][nf] = __builtin_amdgcn_mfma_f32_16x16x32_bf16(q, hv[nf], acc[bf][nf], 0, 0, 0);
        }
    }
    #pragma unroll
    for (int bf=0; bf<8; bf++){
        int b = w*128 + bf*16 + lg*4;
        #pragma unroll
        for (int nf=0; nf<4; nf++){
            int n = n0 + nf*16 + lr;
            if (n >= N_ENT) continue;
            #pragma unroll
            for (int j=0; j<4; j++){
                out[(size_t)(b+j)*N_ENT + n] = acc[bf][nf][j];
            }
        }
    }
}

extern "C" void kernel_launch(void* const* d_in, const int* in_sizes, int n_in,
                              void* d_out, int out_size, void* d_ws, size_t ws_size,
                              hipStream_t stream) {
    const float* ent    = (const float*)d_in[0];
    const float* rel    = (const float*)d_in[1];
    const float* Wn1    = (const float*)d_in[2];
    const float* Wl1    = (const float*)d_in[3];
    const float* Wn2    = (const float*)d_in[4];
    const float* Wl2    = (const float*)d_in[5];
    const float* gtheta = (const float*)d_in[6];
    const float* gw     = (const float*)d_in[7];
    const float* gb     = (const float*)d_in[8];
    const float* gamma  = (const float*)d_in[9];
    const float* beta   = (const float*)d_in[10];
    const float* convw  = (const float*)d_in[11];
    const float* convb  = (const float*)d_in[12];
    const float* freq   = (const float*)d_in[13];
    const int*   src    = (const int*)d_in[14];
    const int*   dst    = (const int*)d_in[15];
    const int*   etype  = (const int*)d_in[16];
    const int*   s_idx  = (const int*)d_in[17];
    const int*   r_idx  = (const int*)d_in[18];
    float* out = (float*)d_out;

    char* ws = (char*)d_ws;
    size_t off = 0;
    auto alloc = [&](size_t bytes)->char*{
        char* p = ws + off;
        off += (bytes + 511) & ~(size_t)511;
        return p;
    };
    int*   deg      = (int*)alloc((size_t)N_ENT*4);
    int*   row_off  = (int*)alloc((size_t)(N_ENT+1)*4);
    int*   fill_pos = (int*)alloc((size_t)N_ENT*4);
    int*   partial  = (int*)alloc((size_t)SCAN_NB*4);
    int2*  cs       = (int2*)alloc((size_t)NEDGE*8);
    unsigned short* A1   = (unsigned short*)alloc((size_t)N_ENT*KPAD*2);
    unsigned short* A2   = (unsigned short*)alloc((size_t)N_ENT*KPAD*2);
    unsigned short* entb = (unsigned short*)alloc((size_t)N_ENT*HDIM*2);
    unsigned short* relb = (unsigned short*)alloc((size_t)460*HDIM*2);
    unsigned short* Bp1  = (unsigned short*)alloc((size_t)13*13*64*8*2);
    unsigned short* Bp2  = (unsigned short*)alloc((size_t)13*13*64*8*2);
    unsigned short* qb   = (unsigned short*)alloc((size_t)BDIM*HPAD*2);
    float* gate   = (float*)alloc((size_t)N_ENT*4);
    float* bnpart = (float*)alloc((size_t)BN_NB*6*4);
    float* bnp    = (float*)alloc(64);
    unsigned short* hfb = A1;   // aliases A1 (dead after gemm1)

    hipMemsetAsync(deg, 0, (size_t)N_ENT*4, stream);

    const int EB = (NEDGE + 255)/256;
    hist_k<<<EB,256,0,stream>>>(dst, deg);
    scan_part_k<<<SCAN_NB,256,0,stream>>>(deg, partial);
    scan_mid_k<<<1,128,0,stream>>>(partial);
    scan_fin_k<<<SCAN_NB,256,0,stream>>>(deg, partial, row_off, fill_pos);
    fill_k<<<EB,256,0,stream>>>(src, dst, etype, fill_pos, cs);

    prep_ent_k<<<N_ENT/4,256,0,stream>>>(ent, A1, A2, entb);
    prep_rel_k<<<(460*HDIM+255)/256,256,0,stream>>>(rel, relb);
    pack_w_k<<<(13*13*64*8+255)/256,256,0,stream>>>(Wn1, Wl1, Bp1);
    pack_w_k<<<(13*13*64*8+255)/256,256,0,stream>>>(Wn2, Wl2, Bp2);

    const int NWB = N_ENT/4;             // spmm: 4 waves/block, 1 node/wave
    const int GTB = (N_ENT + 127)/128;   // gemm: 128-row tiles

    // layer 1
    spmm_bf_k<<<NWB,256,0,stream>>>(A1, relb, cs, row_off);
    gemm_layer_mfma_k<1><<<GTB,256,0,stream>>>(A1, Bp1, A2, nullptr, nullptr);

    zero_hfb_pad_k<<<(N_ENT*24+255)/256,256,0,stream>>>(hfb);
    gate_k<<<NWB,256,0,stream>>>(gtheta, gw, gb, gate);

    // layer 2 (+ gate blend)
    spmm_bf_k<<<NWB,256,0,stream>>>(A2, relb, cs, row_off);
    gemm_layer_mfma_k<2><<<GTB,256,0,stream>>>(A2, Bp2, hfb, gate, entb);

    // ConvE head
    bn_part_k<<<BN_NB,256,0,stream>>>(hfb, rel, freq, s_idx, r_idx, bnpart);
    bn_fin_k<<<1,64,0,stream>>>(bnpart, bnp);
    qt_k<<<(BDIM*HPAD+255)/256,256,0,stream>>>(hfb, rel, freq, s_idx, r_idx, gamma, beta, convw, convb, bnp, qb);

    // scores
    scores_mfma_k<<<(N_ENT+63)/64,256,0,stream>>>(hfb, qb, out);

    (void)in_sizes; (void)n_in; (void)out_size; (void)ws_size;
}

// Round 5
// 627.787 us; speedup vs baseline: 3.2783x; 1.1214x over previous
//
#include <hip/hip_runtime.h>

#define N_ENT 100000
#define HDIM  200
#define NEDGE 1000000
#define BDIM  512
#define KPAD  416    // [P(200) pad(8) X(200) pad(8)]
#define NPAD  208    // 13 x 16
#define HPAD  224    // 7 x 32 (K for scores)
#define SCAN_TILE 1024
#define SCAN_NB   ((N_ENT + SCAN_TILE - 1)/SCAN_TILE)   // 98
#define BN_NB 32

typedef short  short8v __attribute__((ext_vector_type(8)));
typedef float  float4v __attribute__((ext_vector_type(4)));

__device__ __forceinline__ float rrelu_f(float v){
    const float slope = (1.0f/8.0f + 1.0f/3.0f)*0.5f;
    return v >= 0.f ? v : v*slope;
}
__device__ __forceinline__ unsigned short f2bf(float f){
    unsigned int x = __float_as_uint(f);
    unsigned int r = (x + 0x7fffu + ((x >> 16) & 1u)) >> 16;
    return (unsigned short)r;
}
__device__ __forceinline__ float bf2f(unsigned short u){
    return __uint_as_float(((unsigned int)u) << 16);
}

// ---- CSR build ----------------------------------------------------------
__global__ void hist_k(const int* __restrict__ dst, int* __restrict__ deg){
    int e = blockIdx.x*blockDim.x + threadIdx.x;
    if (e < NEDGE) atomicAdd(&deg[dst[e]], 1);
}

__global__ __launch_bounds__(256) void scan_part_k(const int* __restrict__ deg, int* __restrict__ partial){
    int t = threadIdx.x;
    int base = blockIdx.x*SCAN_TILE + t*4;
    int s = 0;
    if (base + 3 < N_ENT){
        int4 v = *(const int4*)(deg + base);
        s = v.x + v.y + v.z + v.w;
    } else {
        for (int i=0;i<4;i++) if (base+i < N_ENT) s += deg[base+i];
    }
    #pragma unroll
    for (int off=32; off>=1; off>>=1) s += __shfl_xor(s, off);
    __shared__ int ws[4];
    if ((t&63)==0) ws[t>>6] = s;
    __syncthreads();
    if (t==0) partial[blockIdx.x] = ws[0]+ws[1]+ws[2]+ws[3];
}

__global__ void scan_mid_k(int* __restrict__ partial){
    __shared__ int sh[128];
    int t = threadIdx.x;
    int v = (t < SCAN_NB) ? partial[t] : 0;
    sh[t] = v;
    __syncthreads();
    for (int off=1; off<128; off<<=1){
        int u = (t>=off) ? sh[t-off] : 0;
        __syncthreads();
        sh[t] += u;
        __syncthreads();
    }
    if (t < SCAN_NB) partial[t] = sh[t] - v;   // exclusive
}

__global__ __launch_bounds__(256) void scan_fin_k(const int* __restrict__ deg, const int* __restrict__ partial,
        int* __restrict__ row_off, int* __restrict__ fill_pos){
    int t = threadIdx.x;
    int lane = t & 63;
    int base = blockIdx.x*SCAN_TILE + t*4;
    int v0=0,v1=0,v2=0,v3=0;
    if (base+3 < N_ENT){
        int4 v = *(const int4*)(deg + base);
        v0=v.x; v1=v.y; v2=v.z; v3=v.w;
    } else {
        if (base   < N_ENT) v0 = deg[base];
        if (base+1 < N_ENT) v1 = deg[base+1];
        if (base+2 < N_ENT) v2 = deg[base+2];
        if (base+3 < N_ENT) v3 = deg[base+3];
    }
    int s = v0+v1+v2+v3;
    int inc = s;
    #pragma unroll
    for (int off=1; off<64; off<<=1){
        int u = __shfl_up(inc, off);
        if (lane >= off) inc += u;
    }
    __shared__ int wsum[4];
    if (lane==63) wsum[t>>6] = inc;
    __syncthreads();
    int w = t>>6;
    int woff = 0;
    for (int i=0;i<w;i++) woff += wsum[i];
    int exc = partial[blockIdx.x] + woff + inc - s;
    int r0 = exc, r1 = exc+v0, r2 = exc+v0+v1, r3 = exc+v0+v1+v2;
    if (base+3 < N_ENT){
        *(int4*)(row_off+base)  = make_int4(r0,r1,r2,r3);
        *(int4*)(fill_pos+base) = make_int4(r0,r1,r2,r3);
    } else {
        if (base   < N_ENT){ row_off[base]  =r0; fill_pos[base]  =r0; }
        if (base+1 < N_ENT){ row_off[base+1]=r1; fill_pos[base+1]=r1; }
        if (base+2 < N_ENT){ row_off[base+2]=r2; fill_pos[base+2]=r2; }
        if (base+3 < N_ENT){ row_off[base+3]=r3; fill_pos[base+3]=r3; }
    }
    if (blockIdx.x==0 && t==0) row_off[N_ENT] = NEDGE;
}

__global__ void fill_k(const int* __restrict__ src, const int* __restrict__ dst, const int* __restrict__ et,
                       int* __restrict__ fill_pos, int2* __restrict__ cs){
    int e = blockIdx.x*blockDim.x + threadIdx.x;
    if (e < NEDGE){
        int p = atomicAdd(&fill_pos[dst[e]], 1);
        cs[p] = make_int2(src[e], et[e]);
    }
}

// ---- prep: ent -> A1 X-section (bf16) + zero pads -----------------------
__global__ __launch_bounds__(256) void prep_ent_k(const float* __restrict__ ent,
        unsigned short* __restrict__ A1, unsigned short* __restrict__ A2){
    int w = threadIdx.x >> 6, l = threadIdx.x & 63;
    int n = blockIdx.x*4 + w;
    if (l < 50){
        float4 v = *(const float4*)(ent + (size_t)n*HDIM + 4*l);
        ushort4 o; o.x=f2bf(v.x); o.y=f2bf(v.y); o.z=f2bf(v.z); o.w=f2bf(v.w);
        *(ushort4*)(A1 + (size_t)n*KPAD + NPAD + 4*l) = o;
    }
    if (l < 8){
        A1[(size_t)n*KPAD + 200 + l] = 0; A1[(size_t)n*KPAD + 408 + l] = 0;
        A2[(size_t)n*KPAD + 200 + l] = 0; A2[(size_t)n*KPAD + 408 + l] = 0;
    }
}

__global__ void prep_rel_k(const float* __restrict__ rel, unsigned short* __restrict__ relb){
    int i = blockIdx.x*blockDim.x + threadIdx.x;
    if (i < 460*HDIM) relb[i] = f2bf(rel[i]);
}

// ---- pack [Wn;Wl] (K=416 x N=208, zero-padded) into MFMA B-frag layout ---
__global__ void pack_w_k(const float* __restrict__ Wn, const float* __restrict__ Wl,
                         unsigned short* __restrict__ Bpack){
    int i = blockIdx.x*blockDim.x + threadIdx.x;
    if (i >= 13*13*64*8) return;
    int j = i & 7, l = (i >> 3) & 63, rest = i >> 9;
    int f = rest % 13, ks = rest / 13;
    int k = ks*32 + ((l >> 4) << 3) + j;
    int c = f*16 + (l & 15);
    float v = 0.f;
    if (c < HDIM){
        if (k < 200)                  v = Wn[(size_t)k*HDIM + c];
        else if (k >= 208 && k < 408) v = Wl[(size_t)(k-208)*HDIM + c];
    }
    Bpack[i] = f2bf(v);
}

// ---- spmm layer 1: gather X + rel, write P1 and relavg ------------------
__global__ __launch_bounds__(256) void spmm1_k(unsigned short* __restrict__ Apack,
        const unsigned short* __restrict__ relb,
        const int2* __restrict__ cs,
        const int* __restrict__ row_off,
        unsigned short* __restrict__ relavg){
    int wv = (blockIdx.x*256 + threadIdx.x) >> 6;
    int l = threadIdx.x & 63;
    if (l >= 50) return;
    int beg = row_off[wv], end = row_off[wv+1];
    const int el = 4*l;
    float x0=0.f,x1=0.f,x2=0.f,x3=0.f;
    float r0=0.f,r1=0.f,r2=0.f,r3=0.f;
    int e = beg;
    for (; e+4 <= end; e+=4){
        int2 c0 = cs[e], c1 = cs[e+1], c2 = cs[e+2], c3 = cs[e+3];
        ushort4 xa = *(const ushort4*)(Apack + (size_t)c0.x*KPAD + NPAD + el);
        ushort4 xb = *(const ushort4*)(Apack + (size_t)c1.x*KPAD + NPAD + el);
        ushort4 xc = *(const ushort4*)(Apack + (size_t)c2.x*KPAD + NPAD + el);
        ushort4 xd = *(const ushort4*)(Apack + (size_t)c3.x*KPAD + NPAD + el);
        ushort4 ra = *(const ushort4*)(relb + (size_t)c0.y*HDIM + el);
        ushort4 rb = *(const ushort4*)(relb + (size_t)c1.y*HDIM + el);
        ushort4 rc = *(const ushort4*)(relb + (size_t)c2.y*HDIM + el);
        ushort4 rd = *(const ushort4*)(relb + (size_t)c3.y*HDIM + el);
        x0 += bf2f(xa.x)+bf2f(xb.x)+bf2f(xc.x)+bf2f(xd.x);
        x1 += bf2f(xa.y)+bf2f(xb.y)+bf2f(xc.y)+bf2f(xd.y);
        x2 += bf2f(xa.z)+bf2f(xb.z)+bf2f(xc.z)+bf2f(xd.z);
        x3 += bf2f(xa.w)+bf2f(xb.w)+bf2f(xc.w)+bf2f(xd.w);
        r0 += bf2f(ra.x)+bf2f(rb.x)+bf2f(rc.x)+bf2f(rd.x);
        r1 += bf2f(ra.y)+bf2f(rb.y)+bf2f(rc.y)+bf2f(rd.y);
        r2 += bf2f(ra.z)+bf2f(rb.z)+bf2f(rc.z)+bf2f(rd.z);
        r3 += bf2f(ra.w)+bf2f(rb.w)+bf2f(rc.w)+bf2f(rd.w);
    }
    for (; e<end; e++){
        int2 c0 = cs[e];
        ushort4 xa = *(const ushort4*)(Apack + (size_t)c0.x*KPAD + NPAD + el);
        ushort4 ra = *(const ushort4*)(relb + (size_t)c0.y*HDIM + el);
        x0 += bf2f(xa.x); x1 += bf2f(xa.y); x2 += bf2f(xa.z); x3 += bf2f(xa.w);
        r0 += bf2f(ra.x); r1 += bf2f(ra.y); r2 += bf2f(ra.z); r3 += bf2f(ra.w);
    }
    float id = 1.f / fmaxf((float)(end-beg), 1.f);
    float g0 = r0*id, g1 = r1*id, g2 = r2*id, g3 = r3*id;
    ushort4 rv; rv.x=f2bf(g0); rv.y=f2bf(g1); rv.z=f2bf(g2); rv.w=f2bf(g3);
    *(ushort4*)(relavg + (size_t)wv*HDIM + el) = rv;
    ushort4 o;
    o.x=f2bf(x0*id+g0); o.y=f2bf(x1*id+g1); o.z=f2bf(x2*id+g2); o.w=f2bf(x3*id+g3);
    *(ushort4*)(Apack + (size_t)wv*KPAD + el) = o;
}

// ---- spmm layer 2: gather X only + stream relavg, write P2 --------------
__global__ __launch_bounds__(256) void spmm2_k(unsigned short* __restrict__ Apack,
        const unsigned short* __restrict__ relavg,
        const int2* __restrict__ cs,
        const int* __restrict__ row_off){
    int wv = (blockIdx.x*256 + threadIdx.x) >> 6;
    int l = threadIdx.x & 63;
    if (l >= 50) return;
    int beg = row_off[wv], end = row_off[wv+1];
    const int el = 4*l;
    float x0=0.f,x1=0.f,x2=0.f,x3=0.f;
    int e = beg;
    for (; e+4 <= end; e+=4){
        int2 c0 = cs[e], c1 = cs[e+1], c2 = cs[e+2], c3 = cs[e+3];
        ushort4 xa = *(const ushort4*)(Apack + (size_t)c0.x*KPAD + NPAD + el);
        ushort4 xb = *(const ushort4*)(Apack + (size_t)c1.x*KPAD + NPAD + el);
        ushort4 xc = *(const ushort4*)(Apack + (size_t)c2.x*KPAD + NPAD + el);
        ushort4 xd = *(const ushort4*)(Apack + (size_t)c3.x*KPAD + NPAD + el);
        x0 += bf2f(xa.x)+bf2f(xb.x)+bf2f(xc.x)+bf2f(xd.x);
        x1 += bf2f(xa.y)+bf2f(xb.y)+bf2f(xc.y)+bf2f(xd.y);
        x2 += bf2f(xa.z)+bf2f(xb.z)+bf2f(xc.z)+bf2f(xd.z);
        x3 += bf2f(xa.w)+bf2f(xb.w)+bf2f(xc.w)+bf2f(xd.w);
    }
    for (; e<end; e++){
        int2 c0 = cs[e];
        ushort4 xa = *(const ushort4*)(Apack + (size_t)c0.x*KPAD + NPAD + el);
        x0 += bf2f(xa.x); x1 += bf2f(xa.y); x2 += bf2f(xa.z); x3 += bf2f(xa.w);
    }
    float id = 1.f / fmaxf((float)(end-beg), 1.f);
    ushort4 rv = *(const ushort4*)(relavg + (size_t)wv*HDIM + el);
    ushort4 o;
    o.x=f2bf(x0*id+bf2f(rv.x)); o.y=f2bf(x1*id+bf2f(rv.y));
    o.z=f2bf(x2*id+bf2f(rv.z)); o.w=f2bf(x3*id+bf2f(rv.w));
    *(ushort4*)(Apack + (size_t)wv*KPAD + el) = o;
}

// ---- gate[n] = sigmoid(gate_theta[n] . gate_w + gate_b) ------------------
__global__ __launch_bounds__(256) void gate_k(const float* __restrict__ th, const float* __restrict__ gw,
                       const float* __restrict__ gb, float* __restrict__ gate){
    int wv = (blockIdx.x*256 + threadIdx.x)>>6;
    int lane = threadIdx.x & 63;
    const float* t = th + (size_t)wv*HDIM;
    float s = t[lane]*gw[lane] + t[64+lane]*gw[64+lane] + t[128+lane]*gw[128+lane];
    if (lane<8) s += t[192+lane]*gw[192+lane];
    #pragma unroll
    for (int off=32; off>=1; off>>=1) s += __shfl_xor(s, off);
    if (lane==0) gate[wv] = 1.f/(1.f + expf(-(s + gb[0])));
}

// ---- layer GEMM via MFMA: Out = act([P|X] @ [Wn;Wl]) ---------------------
// 128 rows/block, 32 rows/wave (2x16 frags). Epilogue through LDS, 16B stores.
template<int EPI>
__global__ __launch_bounds__(256,2) void gemm_layer_mfma_k(
        const unsigned short* __restrict__ Apack,
        const unsigned short* __restrict__ Bpack,
        unsigned short* __restrict__ OutB,
        const float* __restrict__ gate, const float* __restrict__ ent){
    __shared__ unsigned short OutS[128*208];
    const int tid = threadIdx.x;
    const int l   = tid & 63;
    const int w   = tid >> 6;
    const int n0  = blockIdx.x * 128;
    const int lr  = l & 15;
    const int lg  = l >> 4;
    int r0 = n0 + w*32 + lr;
    int r1 = r0 + 16;
    int c0 = r0 < N_ENT ? r0 : N_ENT-1;
    int c1 = r1 < N_ENT ? r1 : N_ENT-1;
    const unsigned short* ar0 = Apack + (size_t)c0*KPAD + lg*8;
    const unsigned short* ar1 = Apack + (size_t)c1*KPAD + lg*8;
    float4v acc[2][13];
    #pragma unroll
    for (int f=0; f<13; f++){
        acc[0][f] = (float4v){0.f,0.f,0.f,0.f};
        acc[1][f] = (float4v){0.f,0.f,0.f,0.f};
    }
    short8v a0 = *(const short8v*)(ar0);
    short8v a1 = *(const short8v*)(ar1);
    for (int ks=0; ks<13; ks++){
        short8v na0 = a0, na1 = a1;
        if (ks < 12){
            na0 = *(const short8v*)(ar0 + (ks+1)*32);
            na1 = *(const short8v*)(ar1 + (ks+1)*32);
        }
        const unsigned short* bp = Bpack + ((size_t)(ks*13)*64 + l)*8;
        #pragma unroll
        for (int f=0; f<13; f++){
            short8v b = *(const short8v*)(bp + (size_t)f*512);
            acc[0][f] = __builtin_amdgcn_mfma_f32_16x16x32_bf16(a0, b, acc[0][f], 0, 0, 0);
            acc[1][f] = __builtin_amdgcn_mfma_f32_16x16x32_bf16(a1, b, acc[1][f], 0, 0, 0);
        }
        a0 = na0; a1 = na1;
    }
    #pragma unroll
    for (int f=0; f<13; f++){
        int c = f*16 + lr;
        if (c < HDIM){
            #pragma unroll
            for (int j=0; j<4; j++){
                OutS[(w*32 + lg*4 + j)*208 + c]      = f2bf(rrelu_f(acc[0][f][j]));
                OutS[(w*32 + 16 + lg*4 + j)*208 + c] = f2bf(rrelu_f(acc[1][f][j]));
            }
        }
    }
    __syncthreads();
    for (int i = tid; i < 128*25; i += 256){
        int r = i/25, seg = i - r*25;
        int n = n0 + r;
        if (n >= N_ENT) continue;
        short8v v = *(const short8v*)(&OutS[r*208 + seg*8]);
        if (EPI == 2){
            float g = gate[n];
            const float4* ef = (const float4*)(ent + (size_t)n*HDIM + seg*8);
            float4 e0 = ef[0], e1 = ef[1];
            float ev[8] = {e0.x,e0.y,e0.z,e0.w,e1.x,e1.y,e1.z,e1.w};
            short8v o;
            #pragma unroll
            for (int j=0; j<8; j++){
                float x = g*bf2f((unsigned short)v[j]) + (1.f-g)*ev[j];
                o[j] = (short)f2bf(x);
            }
            *(short8v*)(OutB + (size_t)n*HPAD + seg*8) = o;
        } else {
            *(short8v*)(OutB + (size_t)n*KPAD + NPAD + seg*8) = v;
        }
    }
}

// ---- zero hfb pad cols [200,224) ----------------------------------------
__global__ void zero_hfb_pad_k(unsigned short* __restrict__ hfb){
    int i = blockIdx.x*blockDim.x + threadIdx.x;
    if (i >= N_ENT*24) return;
    int n = i / 24, c = 200 + (i - n*24);
    hfb[(size_t)n*HPAD + c] = 0;
}

// ---- BN stats: stage 1 (32-block deterministic partial sums) ------------
__global__ __launch_bounds__(256) void bn_part_k(const unsigned short* __restrict__ hfb,
        const float* __restrict__ rel, const float* __restrict__ freq,
        const int* __restrict__ s_idx, const int* __restrict__ r_idx,
        float* __restrict__ bnpart){
    int t = threadIdx.x;
    float acc[6] = {0,0,0,0,0,0};
    for (int i = blockIdx.x*256 + t; i < BDIM*HDIM; i += BN_NB*256){
        int b = i/HDIM, h = i - b*HDIM;
        float e = bf2f(hfb[(size_t)s_idx[b]*HPAD + h]);
        float r = rel[(size_t)r_idx[b]*HDIM + h];
        float f = freq[i];
        acc[0]+=e; acc[1]+=e*e; acc[2]+=r; acc[3]+=r*r; acc[4]+=f; acc[5]+=f*f;
    }
    __shared__ float red[4][6];
    #pragma unroll
    for (int c=0;c<6;c++){
        float s = acc[c];
        #pragma unroll
        for (int off=32; off>=1; off>>=1) s += __shfl_xor(s, off);
        if ((t&63)==0) red[t>>6][c] = s;
    }
    __syncthreads();
    if (t==0){
        #pragma unroll
        for (int c=0;c<6;c++)
            bnpart[blockIdx.x*6+c] = red[0][c]+red[1][c]+red[2][c]+red[3][c];
    }
}

__global__ void bn_fin_k(const float* __restrict__ bnpart, float* __restrict__ bnp){
    int t = threadIdx.x;
    if (t < 3){
        float s=0.f, q=0.f;
        for (int b=0;b<BN_NB;b++){ s += bnpart[b*6+2*t]; q += bnpart[b*6+2*t+1]; }
        const float inv = 1.f/(float)(BDIM*HDIM);
        float mean = s*inv;
        float var  = q*inv - mean*mean;
        bnp[t]   = mean;
        bnp[3+t] = rsqrtf(var + 1e-5f);
    }
}

// ---- q row-major bf16 [512][HPAD], pads zeroed --------------------------
__global__ void qt_k(const unsigned short* __restrict__ hfb, const float* __restrict__ rel,
        const float* __restrict__ freq, const int* __restrict__ s_idx, const int* __restrict__ r_idx,
        const float* __restrict__ gamma, const float* __restrict__ beta,
        const float* __restrict__ convw, const float* __restrict__ convb,
        const float* __restrict__ bnp, unsigned short* __restrict__ qb){
    int i = blockIdx.x*blockDim.x + threadIdx.x;
    if (i >= BDIM*HPAD) return;
    int b = i/HPAD, h = i - b*HPAD;
    if (h >= HDIM){ qb[i] = 0; return; }
    float x0 = bf2f(hfb[(size_t)s_idx[b]*HPAD + h]);
    float x1 = rel[(size_t)r_idx[b]*HDIM + h];
    float x2 = freq[(size_t)b*HDIM + h];
    float v0 = fmaxf((x0-bnp[0])*bnp[3]*gamma[0] + beta[0], 0.f);
    float v1 = fmaxf((x1-bnp[1])*bnp[4]*gamma[1] + beta[1], 0.f);
    float v2 = fmaxf((x2-bnp[2])*bnp[5]*gamma[2] + beta[2], 0.f);
    float q = v0*convw[0] + v1*convw[1] + v2*convw[2] + convb[0];
    qb[(size_t)b*HPAD + h] = f2bf(q);
}

// ---- scores[b][n] = q[b] . hf[n] via MFMA, 64-row n-tiles ---------------
__global__ __launch_bounds__(256,2) void scores_mfma_k(
        const unsigned short* __restrict__ hfb,
        const unsigned short* __restrict__ qb,
        float* __restrict__ out){
    const int tid = threadIdx.x;
    const int l   = tid & 63;
    const int w   = tid >> 6;
    const int lr  = l & 15;
    const int lg  = l >> 4;
    const int n0  = blockIdx.x * 64;
    float4v acc[8][4];
    #pragma unroll
    for (int bf=0; bf<8; bf++)
        #pragma unroll
        for (int nf=0; nf<4; nf++) acc[bf][nf] = (float4v){0,0,0,0};
    const unsigned short* hptr[4];
    #pragma unroll
    for (int nf=0; nf<4; nf++){
        int n = n0 + nf*16 + lr;
        if (n >= N_ENT) n = N_ENT-1;
        hptr[nf] = hfb + (size_t)n*HPAD + lg*8;
    }
    const unsigned short* qrow = qb + (size_t)(w*128 + lr)*HPAD + lg*8;
    for (int ks=0; ks<7; ks++){
        short8v hv[4];
        #pragma unroll
        for (int nf=0; nf<4; nf++) hv[nf] = *(const short8v*)(hptr[nf] + ks*32);
        #pragma unroll
        for (int bf=0; bf<8; bf++){
            short8v q = *(const short8v*)(qrow + (size_t)bf*16*HPAD + ks*32);
            #pragma unroll
            for (int nf=0; nf<4; nf++)
                acc[bf][nf] = __builtin_amdgcn_mfma_f32_16x16x32_bf16(q, hv[nf], acc[bf][nf], 0, 0, 0);
        }
    }
    #pragma unroll
    for (int bf=0; bf<8; bf++){
        int b = w*128 + bf*16 + lg*4;
        #pragma unroll
        for (int nf=0; nf<4; nf++){
            int n = n0 + nf*16 + lr;
            if (n >= N_ENT) continue;
            #pragma unroll
            for (int j=0; j<4; j++){
                out[(size_t)(b+j)*N_ENT + n] = acc[bf][nf][j];
            }
        }
    }
}

extern "C" void kernel_launch(void* const* d_in, const int* in_sizes, int n_in,
                              void* d_out, int out_size, void* d_ws, size_t ws_size,
                              hipStream_t stream) {
    const float* ent    = (const float*)d_in[0];
    const float* rel    = (const float*)d_in[1];
    const float* Wn1    = (const float*)d_in[2];
    const float* Wl1    = (const float*)d_in[3];
    const float* Wn2    = (const float*)d_in[4];
    const float* Wl2    = (const float*)d_in[5];
    const float* gtheta = (const float*)d_in[6];
    const float* gw     = (const float*)d_in[7];
    const float* gb     = (const float*)d_in[8];
    const float* gamma  = (const float*)d_in[9];
    const float* beta   = (const float*)d_in[10];
    const float* convw  = (const float*)d_in[11];
    const float* convb  = (const float*)d_in[12];
    const float* freq   = (const float*)d_in[13];
    const int*   src    = (const int*)d_in[14];
    const int*   dst    = (const int*)d_in[15];
    const int*   etype  = (const int*)d_in[16];
    const int*   s_idx  = (const int*)d_in[17];
    const int*   r_idx  = (const int*)d_in[18];
    float* out = (float*)d_out;

    char* ws = (char*)d_ws;
    size_t off = 0;
    auto alloc = [&](size_t bytes)->char*{
        char* p = ws + off;
        off += (bytes + 511) & ~(size_t)511;
        return p;
    };
    int*   deg      = (int*)alloc((size_t)N_ENT*4);
    int*   row_off  = (int*)alloc((size_t)(N_ENT+1)*4);
    int*   fill_pos = (int*)alloc((size_t)N_ENT*4);
    int*   partial  = (int*)alloc((size_t)SCAN_NB*4);
    int2*  cs       = (int2*)alloc((size_t)NEDGE*8);
    unsigned short* A1     = (unsigned short*)alloc((size_t)N_ENT*KPAD*2);
    unsigned short* A2     = (unsigned short*)alloc((size_t)N_ENT*KPAD*2);
    unsigned short* relavg = (unsigned short*)alloc((size_t)N_ENT*HDIM*2);
    unsigned short* relb   = (unsigned short*)alloc((size_t)460*HDIM*2);
    unsigned short* Bp1    = (unsigned short*)alloc((size_t)13*13*64*8*2);
    unsigned short* Bp2    = (unsigned short*)alloc((size_t)13*13*64*8*2);
    unsigned short* qb     = (unsigned short*)alloc((size_t)BDIM*HPAD*2);
    float* gate   = (float*)alloc((size_t)N_ENT*4);
    float* bnpart = (float*)alloc((size_t)BN_NB*6*4);
    float* bnp    = (float*)alloc(64);
    unsigned short* hfb = A1;   // aliases A1 (dead after gemm1)

    hipMemsetAsync(deg, 0, (size_t)N_ENT*4, stream);

    const int EB = (NEDGE + 255)/256;
    hist_k<<<EB,256,0,stream>>>(dst, deg);
    scan_part_k<<<SCAN_NB,256,0,stream>>>(deg, partial);
    scan_mid_k<<<1,128,0,stream>>>(partial);
    scan_fin_k<<<SCAN_NB,256,0,stream>>>(deg, partial, row_off, fill_pos);
    fill_k<<<EB,256,0,stream>>>(src, dst, etype, fill_pos, cs);

    prep_ent_k<<<N_ENT/4,256,0,stream>>>(ent, A1, A2);
    prep_rel_k<<<(460*HDIM+255)/256,256,0,stream>>>(rel, relb);
    pack_w_k<<<(13*13*64*8+255)/256,256,0,stream>>>(Wn1, Wl1, Bp1);
    pack_w_k<<<(13*13*64*8+255)/256,256,0,stream>>>(Wn2, Wl2, Bp2);

    const int NWB = N_ENT/4;             // spmm: 4 waves/block, 1 node/wave
    const int GTB = (N_ENT + 127)/128;   // gemm: 128-row tiles

    // layer 1 (also emits relavg = relsum*invdeg, reused by layer 2)
    spmm1_k<<<NWB,256,0,stream>>>(A1, relb, cs, row_off, relavg);
    gemm_layer_mfma_k<1><<<GTB,256,0,stream>>>(A1, Bp1, A2, nullptr, nullptr);

    zero_hfb_pad_k<<<(N_ENT*24+255)/256,256,0,stream>>>(hfb);
    gate_k<<<NWB,256,0,stream>>>(gtheta, gw, gb, gate);

    // layer 2 (+ gate blend)
    spmm2_k<<<NWB,256,0,stream>>>(A2, relavg, cs, row_off);
    gemm_layer_mfma_k<2><<<GTB,256,0,stream>>>(A2, Bp2, hfb, gate, ent);

    // ConvE head
    bn_part_k<<<BN_NB,256,0,stream>>>(hfb, rel, freq, s_idx, r_idx, bnpart);
    bn_fin_k<<<1,64,0,stream>>>(bnpart, bnp);
    qt_k<<<(BDIM*HPAD+255)/256,256,0,stream>>>(hfb, rel, freq, s_idx, r_idx, gamma, beta, convw, convb, bnp, qb);

    // scores
    scores_mfma_k<<<(N_ENT+63)/64,256,0,stream>>>(hfb, qb, out);

    (void)in_sizes; (void)n_in; (void)out_size; (void)ws_size;
}

// Round 6
// 574.308 us; speedup vs baseline: 3.5835x; 1.0931x over previous
//
#include <hip/hip_runtime.h>

#define N_ENT 100000
#define HDIM  200
#define NEDGE 1000000
#define BDIM  512
#define PITCH 224            // row pitch (bf16 elems) for P/X/relavg/hfb/qb; 448B, 64B-aligned
#define NSEG  28             // PITCH/8
#define NF    13             // 13 x 16 = 208 output cols
#define SCAN_TILE 1024
#define SCAN_NB   ((N_ENT + SCAN_TILE - 1)/SCAN_TILE)   // 98
#define BN_NB 32
#define RELB_ELEMS (460*PITCH)
#define BP_ELEMS   (14*NF*64*8)   // 93184

typedef short  short8v __attribute__((ext_vector_type(8)));
typedef float  float4v __attribute__((ext_vector_type(4)));

__device__ __forceinline__ float rrelu_f(float v){
    const float slope = (1.0f/8.0f + 1.0f/3.0f)*0.5f;
    return v >= 0.f ? v : v*slope;
}
__device__ __forceinline__ unsigned short f2bf(float f){
    unsigned int x = __float_as_uint(f);
    unsigned int r = (x + 0x7fffu + ((x >> 16) & 1u)) >> 16;
    return (unsigned short)r;
}
__device__ __forceinline__ float bf2f(unsigned short u){
    return __uint_as_float(((unsigned int)u) << 16);
}

// ---- fused init: zero deg | relb | Bp1 | Bp2 | Xbuf1=bf16(ent) ----------
__device__ __forceinline__ void pack_b(int b, const float* __restrict__ Wn,
        const float* __restrict__ Wl, unsigned short* __restrict__ Bp){
    int i = b*1024 + threadIdx.x*4;
    #pragma unroll
    for (int k=0;k<4;k++){
        int idx = i+k;
        if (idx < BP_ELEMS){
            int j = idx & 7, l = (idx >> 3) & 63, rest = idx >> 9;
            int f = rest % NF, ks = rest / NF;
            int kk = ks*32 + ((l >> 4) << 3) + j;
            int c  = f*16 + (l & 15);
            float v = 0.f;
            if (c < HDIM){
                if (kk < 200)                  v = Wn[(size_t)kk*HDIM + c];
                else if (kk >= 224 && kk < 424) v = Wl[(size_t)(kk-224)*HDIM + c];
            }
            Bp[idx] = f2bf(v);
        }
    }
}

__global__ __launch_bounds__(256) void init_k(const float* __restrict__ ent,
        const float* __restrict__ rel,
        const float* __restrict__ Wn1, const float* __restrict__ Wl1,
        const float* __restrict__ Wn2, const float* __restrict__ Wl2,
        int* __restrict__ deg, unsigned short* __restrict__ relb,
        unsigned short* __restrict__ Bp1, unsigned short* __restrict__ Bp2,
        unsigned short* __restrict__ Xbuf1){
    int b = blockIdx.x;
    if (b < 98){
        int i = b*1024 + threadIdx.x*4;
        if (i+3 < N_ENT) *(int4*)(deg+i) = make_int4(0,0,0,0);
        else { for (int k=0;k<4;k++) if (i+k < N_ENT) deg[i+k]=0; }
        return;
    }
    b -= 98;
    if (b < 101){
        int i = b*1024 + threadIdx.x*4;
        #pragma unroll
        for (int k=0;k<4;k++){
            int idx = i+k;
            if (idx < RELB_ELEMS){
                int r = idx / PITCH, c = idx - r*PITCH;
                relb[idx] = (c < HDIM) ? f2bf(rel[(size_t)r*HDIM + c]) : 0;
            }
        }
        return;
    }
    b -= 101;
    if (b < 91){ pack_b(b, Wn1, Wl1, Bp1); return; }
    b -= 91;
    if (b < 91){ pack_b(b, Wn2, Wl2, Bp2); return; }
    b -= 91;
    // Xbuf1: 4 rows/block
    int w = threadIdx.x >> 6, l = threadIdx.x & 63;
    if (l >= 56) return;
    int n = b*4 + w;
    int el = 4*l;
    ushort4 o;
    if (el < HDIM){
        float4 v = *(const float4*)(ent + (size_t)n*HDIM + el);
        o.x=f2bf(v.x); o.y=f2bf(v.y); o.z=f2bf(v.z); o.w=f2bf(v.w);
    } else {
        o.x=o.y=o.z=o.w=0;
    }
    *(ushort4*)(Xbuf1 + (size_t)n*PITCH + el) = o;
}

// ---- CSR build ----------------------------------------------------------
__global__ void hist_k(const int* __restrict__ dst, int* __restrict__ deg){
    int e = blockIdx.x*blockDim.x + threadIdx.x;
    if (e < NEDGE) atomicAdd(&deg[dst[e]], 1);
}

__global__ __launch_bounds__(256) void scan_part_k(const int* __restrict__ deg, int* __restrict__ partial){
    int t = threadIdx.x;
    int base = blockIdx.x*SCAN_TILE + t*4;
    int s = 0;
    if (base + 3 < N_ENT){
        int4 v = *(const int4*)(deg + base);
        s = v.x + v.y + v.z + v.w;
    } else {
        for (int i=0;i<4;i++) if (base+i < N_ENT) s += deg[base+i];
    }
    #pragma unroll
    for (int off=32; off>=1; off>>=1) s += __shfl_xor(s, off);
    __shared__ int ws[4];
    if ((t&63)==0) ws[t>>6] = s;
    __syncthreads();
    if (t==0) partial[blockIdx.x] = ws[0]+ws[1]+ws[2]+ws[3];
}

__global__ void scan_mid_k(int* __restrict__ partial){
    __shared__ int sh[128];
    int t = threadIdx.x;
    int v = (t < SCAN_NB) ? partial[t] : 0;
    sh[t] = v;
    __syncthreads();
    for (int off=1; off<128; off<<=1){
        int u = (t>=off) ? sh[t-off] : 0;
        __syncthreads();
        sh[t] += u;
        __syncthreads();
    }
    if (t < SCAN_NB) partial[t] = sh[t] - v;   // exclusive
}

__global__ __launch_bounds__(256) void scan_fin_k(const int* __restrict__ deg, const int* __restrict__ partial,
        int* __restrict__ row_off, int* __restrict__ fill_pos){
    int t = threadIdx.x;
    int lane = t & 63;
    int base = blockIdx.x*SCAN_TILE + t*4;
    int v0=0,v1=0,v2=0,v3=0;
    if (base+3 < N_ENT){
        int4 v = *(const int4*)(deg + base);
        v0=v.x; v1=v.y; v2=v.z; v3=v.w;
    } else {
        if (base   < N_ENT) v0 = deg[base];
        if (base+1 < N_ENT) v1 = deg[base+1];
        if (base+2 < N_ENT) v2 = deg[base+2];
        if (base+3 < N_ENT) v3 = deg[base+3];
    }
    int s = v0+v1+v2+v3;
    int inc = s;
    #pragma unroll
    for (int off=1; off<64; off<<=1){
        int u = __shfl_up(inc, off);
        if (lane >= off) inc += u;
    }
    __shared__ int wsum[4];
    if (lane==63) wsum[t>>6] = inc;
    __syncthreads();
    int w = t>>6;
    int woff = 0;
    for (int i=0;i<w;i++) woff += wsum[i];
    int exc = partial[blockIdx.x] + woff + inc - s;
    int r0 = exc, r1 = exc+v0, r2 = exc+v0+v1, r3 = exc+v0+v1+v2;
    if (base+3 < N_ENT){
        *(int4*)(row_off+base)  = make_int4(r0,r1,r2,r3);
        *(int4*)(fill_pos+base) = make_int4(r0,r1,r2,r3);
    } else {
        if (base   < N_ENT){ row_off[base]  =r0; fill_pos[base]  =r0; }
        if (base+1 < N_ENT){ row_off[base+1]=r1; fill_pos[base+1]=r1; }
        if (base+2 < N_ENT){ row_off[base+2]=r2; fill_pos[base+2]=r2; }
        if (base+3 < N_ENT){ row_off[base+3]=r3; fill_pos[base+3]=r3; }
    }
    if (blockIdx.x==0 && t==0) row_off[N_ENT] = NEDGE;
}

__global__ void fill_k(const int* __restrict__ src, const int* __restrict__ dst, const int* __restrict__ et,
                       int* __restrict__ fill_pos, int2* __restrict__ cs){
    int e = blockIdx.x*blockDim.x + threadIdx.x;
    if (e < NEDGE){
        int p = atomicAdd(&fill_pos[dst[e]], 1);
        cs[p] = make_int2(src[e], et[e]);
    }
}

// ---- spmm layer 1: gather X + rel, write P1 and relavg ------------------
__global__ __launch_bounds__(256) void spmm1_k(const unsigned short* __restrict__ X,
        unsigned short* __restrict__ P,
        const unsigned short* __restrict__ relb,
        const int2* __restrict__ cs,
        const int* __restrict__ row_off,
        unsigned short* __restrict__ relavg){
    int wv = (blockIdx.x*256 + threadIdx.x) >> 6;
    int l = threadIdx.x & 63;
    if (l >= 56) return;
    int beg = row_off[wv], end = row_off[wv+1];
    const int el = 4*l;
    float x0=0.f,x1=0.f,x2=0.f,x3=0.f;
    float r0=0.f,r1=0.f,r2=0.f,r3=0.f;
    int e = beg;
    for (; e+4 <= end; e+=4){
        int2 c0 = cs[e], c1 = cs[e+1], c2 = cs[e+2], c3 = cs[e+3];
        ushort4 xa = *(const ushort4*)(X + (size_t)c0.x*PITCH + el);
        ushort4 xb = *(const ushort4*)(X + (size_t)c1.x*PITCH + el);
        ushort4 xc = *(const ushort4*)(X + (size_t)c2.x*PITCH + el);
        ushort4 xd = *(const ushort4*)(X + (size_t)c3.x*PITCH + el);
        ushort4 ra = *(const ushort4*)(relb + (size_t)c0.y*PITCH + el);
        ushort4 rb = *(const ushort4*)(relb + (size_t)c1.y*PITCH + el);
        ushort4 rc = *(const ushort4*)(relb + (size_t)c2.y*PITCH + el);
        ushort4 rd = *(const ushort4*)(relb + (size_t)c3.y*PITCH + el);
        x0 += bf2f(xa.x)+bf2f(xb.x)+bf2f(xc.x)+bf2f(xd.x);
        x1 += bf2f(xa.y)+bf2f(xb.y)+bf2f(xc.y)+bf2f(xd.y);
        x2 += bf2f(xa.z)+bf2f(xb.z)+bf2f(xc.z)+bf2f(xd.z);
        x3 += bf2f(xa.w)+bf2f(xb.w)+bf2f(xc.w)+bf2f(xd.w);
        r0 += bf2f(ra.x)+bf2f(rb.x)+bf2f(rc.x)+bf2f(rd.x);
        r1 += bf2f(ra.y)+bf2f(rb.y)+bf2f(rc.y)+bf2f(rd.y);
        r2 += bf2f(ra.z)+bf2f(rb.z)+bf2f(rc.z)+bf2f(rd.z);
        r3 += bf2f(ra.w)+bf2f(rb.w)+bf2f(rc.w)+bf2f(rd.w);
    }
    for (; e<end; e++){
        int2 c0 = cs[e];
        ushort4 xa = *(const ushort4*)(X + (size_t)c0.x*PITCH + el);
        ushort4 ra = *(const ushort4*)(relb + (size_t)c0.y*PITCH + el);
        x0 += bf2f(xa.x); x1 += bf2f(xa.y); x2 += bf2f(xa.z); x3 += bf2f(xa.w);
        r0 += bf2f(ra.x); r1 += bf2f(ra.y); r2 += bf2f(ra.z); r3 += bf2f(ra.w);
    }
    float id = 1.f / fmaxf((float)(end-beg), 1.f);
    float g0 = r0*id, g1 = r1*id, g2 = r2*id, g3 = r3*id;
    ushort4 rv; rv.x=f2bf(g0); rv.y=f2bf(g1); rv.z=f2bf(g2); rv.w=f2bf(g3);
    *(ushort4*)(relavg + (size_t)wv*PITCH + el) = rv;
    ushort4 o;
    o.x=f2bf(x0*id+g0); o.y=f2bf(x1*id+g1); o.z=f2bf(x2*id+g2); o.w=f2bf(x3*id+g3);
    *(ushort4*)(P + (size_t)wv*PITCH + el) = o;
}

// ---- spmm layer 2: gather X only + stream relavg, write P2 --------------
__global__ __launch_bounds__(256) void spmm2_k(const unsigned short* __restrict__ X,
        unsigned short* __restrict__ P,
        const unsigned short* __restrict__ relavg,
        const int2* __restrict__ cs,
        const int* __restrict__ row_off){
    int wv = (blockIdx.x*256 + threadIdx.x) >> 6;
    int l = threadIdx.x & 63;
    if (l >= 56) return;
    int beg = row_off[wv], end = row_off[wv+1];
    const int el = 4*l;
    float x0=0.f,x1=0.f,x2=0.f,x3=0.f;
    int e = beg;
    for (; e+4 <= end; e+=4){
        int2 c0 = cs[e], c1 = cs[e+1], c2 = cs[e+2], c3 = cs[e+3];
        ushort4 xa = *(const ushort4*)(X + (size_t)c0.x*PITCH + el);
        ushort4 xb = *(const ushort4*)(X + (size_t)c1.x*PITCH + el);
        ushort4 xc = *(const ushort4*)(X + (size_t)c2.x*PITCH + el);
        ushort4 xd = *(const ushort4*)(X + (size_t)c3.x*PITCH + el);
        x0 += bf2f(xa.x)+bf2f(xb.x)+bf2f(xc.x)+bf2f(xd.x);
        x1 += bf2f(xa.y)+bf2f(xb.y)+bf2f(xc.y)+bf2f(xd.y);
        x2 += bf2f(xa.z)+bf2f(xb.z)+bf2f(xc.z)+bf2f(xd.z);
        x3 += bf2f(xa.w)+bf2f(xb.w)+bf2f(xc.w)+bf2f(xd.w);
    }
    for (; e<end; e++){
        int2 c0 = cs[e];
        ushort4 xa = *(const ushort4*)(X + (size_t)c0.x*PITCH + el);
        x0 += bf2f(xa.x); x1 += bf2f(xa.y); x2 += bf2f(xa.z); x3 += bf2f(xa.w);
    }
    float id = 1.f / fmaxf((float)(end-beg), 1.f);
    ushort4 rv = *(const ushort4*)(relavg + (size_t)wv*PITCH + el);
    ushort4 o;
    o.x=f2bf(x0*id+bf2f(rv.x)); o.y=f2bf(x1*id+bf2f(rv.y));
    o.z=f2bf(x2*id+bf2f(rv.z)); o.w=f2bf(x3*id+bf2f(rv.w));
    *(ushort4*)(P + (size_t)wv*PITCH + el) = o;
}

// ---- gate[n] = sigmoid(gate_theta[n] . gate_w + gate_b) ------------------
__global__ __launch_bounds__(256) void gate_k(const float* __restrict__ th, const float* __restrict__ gw,
                       const float* __restrict__ gb, float* __restrict__ gate){
    int wv = (blockIdx.x*256 + threadIdx.x)>>6;
    int lane = threadIdx.x & 63;
    const float* t = th + (size_t)wv*HDIM;
    float s = t[lane]*gw[lane] + t[64+lane]*gw[64+lane] + t[128+lane]*gw[128+lane];
    if (lane<8) s += t[192+lane]*gw[192+lane];
    #pragma unroll
    for (int off=32; off>=1; off>>=1) s += __shfl_xor(s, off);
    if (lane==0) gate[wv] = 1.f/(1.f + expf(-(s + gb[0])));
}

// ---- layer GEMM via MFMA: Out = act([P|X] @ [Wn;Wl]), K=448 --------------
// 128 rows/block, 32 rows/wave. Epilogue via LDS, 16B stores, pads zeroed.
template<int EPI>
__global__ __launch_bounds__(256,2) void gemm_layer_mfma_k(
        const unsigned short* __restrict__ Pb,
        const unsigned short* __restrict__ Xb,
        const unsigned short* __restrict__ Bpack,
        unsigned short* __restrict__ OutB,
        const float* __restrict__ gate, const float* __restrict__ ent){
    __shared__ unsigned short OutS[128*PITCH];
    const int tid = threadIdx.x;
    const int l   = tid & 63;
    const int w   = tid >> 6;
    const int n0  = blockIdx.x * 128;
    const int lr  = l & 15;
    const int lg  = l >> 4;
    int r0 = n0 + w*32 + lr;
    int r1 = r0 + 16;
    int c0 = r0 < N_ENT ? r0 : N_ENT-1;
    int c1 = r1 < N_ENT ? r1 : N_ENT-1;
    float4v acc[2][NF];
    #pragma unroll
    for (int f=0; f<NF; f++){
        acc[0][f] = (float4v){0.f,0.f,0.f,0.f};
        acc[1][f] = (float4v){0.f,0.f,0.f,0.f};
    }
    #pragma unroll 1
    for (int sec=0; sec<2; sec++){
        const unsigned short* base = sec ? Xb : Pb;
        const unsigned short* a0p = base + (size_t)c0*PITCH + lg*8;
        const unsigned short* a1p = base + (size_t)c1*PITCH + lg*8;
        const unsigned short* bp0 = Bpack + (((size_t)(sec*7*NF))*64 + l)*8;
        for (int ks=0; ks<7; ks++){
            short8v a0 = *(const short8v*)(a0p + ks*32);
            short8v a1 = *(const short8v*)(a1p + ks*32);
            const unsigned short* bp = bp0 + (size_t)ks*NF*512;
            #pragma unroll
            for (int f=0; f<NF; f++){
                short8v b = *(const short8v*)(bp + (size_t)f*512);
                acc[0][f] = __builtin_amdgcn_mfma_f32_16x16x32_bf16(a0, b, acc[0][f], 0, 0, 0);
                acc[1][f] = __builtin_amdgcn_mfma_f32_16x16x32_bf16(a1, b, acc[1][f], 0, 0, 0);
            }
        }
    }
    #pragma unroll
    for (int f=0; f<NF; f++){
        int c = f*16 + lr;
        if (c < HDIM){
            #pragma unroll
            for (int j=0; j<4; j++){
                OutS[(w*32 + lg*4 + j)*PITCH + c]      = f2bf(rrelu_f(acc[0][f][j]));
                OutS[(w*32 + 16 + lg*4 + j)*PITCH + c] = f2bf(rrelu_f(acc[1][f][j]));
            }
        }
    }
    __syncthreads();
    for (int i = tid; i < 128*NSEG; i += 256){
        int r = i/NSEG, seg = i - r*NSEG;
        int n = n0 + r;
        if (n >= N_ENT) continue;
        short8v o;
        if (seg >= 25){
            #pragma unroll
            for (int j=0;j<8;j++) o[j]=0;
        } else {
            short8v v = *(const short8v*)(&OutS[r*PITCH + seg*8]);
            if (EPI == 2){
                float g = gate[n];
                const float4* ef = (const float4*)(ent + (size_t)n*HDIM + seg*8);
                float4 e0 = ef[0], e1 = ef[1];
                float ev[8] = {e0.x,e0.y,e0.z,e0.w,e1.x,e1.y,e1.z,e1.w};
                #pragma unroll
                for (int j=0; j<8; j++){
                    float x = g*bf2f((unsigned short)v[j]) + (1.f-g)*ev[j];
                    o[j] = (short)f2bf(x);
                }
            } else {
                o = v;
            }
        }
        *(short8v*)(OutB + (size_t)n*PITCH + seg*8) = o;
    }
}

// ---- BN stats: stage 1 (32-block deterministic partial sums) ------------
__global__ __launch_bounds__(256) void bn_part_k(const unsigned short* __restrict__ hfb,
        const float* __restrict__ rel, const float* __restrict__ freq,
        const int* __restrict__ s_idx, const int* __restrict__ r_idx,
        float* __restrict__ bnpart){
    int t = threadIdx.x;
    float acc[6] = {0,0,0,0,0,0};
    for (int i = blockIdx.x*256 + t; i < BDIM*HDIM; i += BN_NB*256){
        int b = i/HDIM, h = i - b*HDIM;
        float e = bf2f(hfb[(size_t)s_idx[b]*PITCH + h]);
        float r = rel[(size_t)r_idx[b]*HDIM + h];
        float f = freq[i];
        acc[0]+=e; acc[1]+=e*e; acc[2]+=r; acc[3]+=r*r; acc[4]+=f; acc[5]+=f*f;
    }
    __shared__ float red[4][6];
    #pragma unroll
    for (int c=0;c<6;c++){
        float s = acc[c];
        #pragma unroll
        for (int off=32; off>=1; off>>=1) s += __shfl_xor(s, off);
        if ((t&63)==0) red[t>>6][c] = s;
    }
    __syncthreads();
    if (t==0){
        #pragma unroll
        for (int c=0;c<6;c++)
            bnpart[blockIdx.x*6+c] = red[0][c]+red[1][c]+red[2][c]+red[3][c];
    }
}

__global__ void bn_fin_k(const float* __restrict__ bnpart, float* __restrict__ bnp){
    int t = threadIdx.x;
    if (t < 3){
        float s=0.f, q=0.f;
        for (int b=0;b<BN_NB;b++){ s += bnpart[b*6+2*t]; q += bnpart[b*6+2*t+1]; }
        const float inv = 1.f/(float)(BDIM*HDIM);
        float mean = s*inv;
        float var  = q*inv - mean*mean;
        bnp[t]   = mean;
        bnp[3+t] = rsqrtf(var + 1e-5f);
    }
}

// ---- q row-major bf16 [512][PITCH], pads zeroed --------------------------
__global__ void qt_k(const unsigned short* __restrict__ hfb, const float* __restrict__ rel,
        const float* __restrict__ freq, const int* __restrict__ s_idx, const int* __restrict__ r_idx,
        const float* __restrict__ gamma, const float* __restrict__ beta,
        const float* __restrict__ convw, const float* __restrict__ convb,
        const float* __restrict__ bnp, unsigned short* __restrict__ qb){
    int i = blockIdx.x*blockDim.x + threadIdx.x;
    if (i >= BDIM*PITCH) return;
    int b = i/PITCH, h = i - b*PITCH;
    if (h >= HDIM){ qb[i] = 0; return; }
    float x0 = bf2f(hfb[(size_t)s_idx[b]*PITCH + h]);
    float x1 = rel[(size_t)r_idx[b]*HDIM + h];
    float x2 = freq[(size_t)b*HDIM + h];
    float v0 = fmaxf((x0-bnp[0])*bnp[3]*gamma[0] + beta[0], 0.f);
    float v1 = fmaxf((x1-bnp[1])*bnp[4]*gamma[1] + beta[1], 0.f);
    float v2 = fmaxf((x2-bnp[2])*bnp[5]*gamma[2] + beta[2], 0.f);
    float q = v0*convw[0] + v1*convw[1] + v2*convw[2] + convb[0];
    qb[(size_t)b*PITCH + h] = f2bf(q);
}

// ---- scores[b][n] = q[b] . hf[n] via MFMA, 64-row n-tiles ---------------
__global__ __launch_bounds__(256,2) void scores_mfma_k(
        const unsigned short* __restrict__ hfb,
        const unsigned short* __restrict__ qb,
        float* __restrict__ out){
    const int tid = threadIdx.x;
    const int l   = tid & 63;
    const int w   = tid >> 6;
    const int lr  = l & 15;
    const int lg  = l >> 4;
    const int n0  = blockIdx.x * 64;
    float4v acc[8][4];
    #pragma unroll
    for (int bf=0; bf<8; bf++)
        #pragma unroll
        for (int nf=0; nf<4; nf++) acc[bf][nf] = (float4v){0,0,0,0};
    const unsigned short* hptr[4];
    #pragma unroll
    for (int nf=0; nf<4; nf++){
        int n = n0 + nf*16 + lr;
        if (n >= N_ENT) n = N_ENT-1;
        hptr[nf] = hfb + (size_t)n*PITCH + lg*8;
    }
    const unsigned short* qrow = qb + (size_t)(w*128 + lr)*PITCH + lg*8;
    for (int ks=0; ks<7; ks++){
        short8v hv[4];
        #pragma unroll
        for (int nf=0; nf<4; nf++) hv[nf] = *(const short8v*)(hptr[nf] + ks*32);
        #pragma unroll
        for (int bf=0; bf<8; bf++){
            short8v q = *(const short8v*)(qrow + (size_t)bf*16*PITCH + ks*32);
            #pragma unroll
            for (int nf=0; nf<4; nf++)
                acc[bf][nf] = __builtin_amdgcn_mfma_f32_16x16x32_bf16(q, hv[nf], acc[bf][nf], 0, 0, 0);
        }
    }
    #pragma unroll
    for (int bf=0; bf<8; bf++){
        int b = w*128 + bf*16 + lg*4;
        #pragma unroll
        for (int nf=0; nf<4; nf++){
            int n = n0 + nf*16 + lr;
            if (n >= N_ENT) continue;
            #pragma unroll
            for (int j=0; j<4; j++){
                out[(size_t)(b+j)*N_ENT + n] = acc[bf][nf][j];
            }
        }
    }
}

extern "C" void kernel_launch(void* const* d_in, const int* in_sizes, int n_in,
                              void* d_out, int out_size, void* d_ws, size_t ws_size,
                              hipStream_t stream) {
    const float* ent    = (const float*)d_in[0];
    const float* rel    = (const float*)d_in[1];
    const float* Wn1    = (const float*)d_in[2];
    const float* Wl1    = (const float*)d_in[3];
    const float* Wn2    = (const float*)d_in[4];
    const float* Wl2    = (const float*)d_in[5];
    const float* gtheta = (const float*)d_in[6];
    const float* gw     = (const float*)d_in[7];
    const float* gb     = (const float*)d_in[8];
    const float* gamma  = (const float*)d_in[9];
    const float* beta   = (const float*)d_in[10];
    const float* convw  = (const float*)d_in[11];
    const float* convb  = (const float*)d_in[12];
    const float* freq   = (const float*)d_in[13];
    const int*   src    = (const int*)d_in[14];
    const int*   dst    = (const int*)d_in[15];
    const int*   etype  = (const int*)d_in[16];
    const int*   s_idx  = (const int*)d_in[17];
    const int*   r_idx  = (const int*)d_in[18];
    float* out = (float*)d_out;

    char* ws = (char*)d_ws;
    size_t off = 0;
    auto alloc = [&](size_t bytes)->char*{
        char* p = ws + off;
        off += (bytes + 511) & ~(size_t)511;
        return p;
    };
    int*   deg      = (int*)alloc((size_t)N_ENT*4);
    int*   row_off  = (int*)alloc((size_t)(N_ENT+1)*4);
    int*   fill_pos = (int*)alloc((size_t)N_ENT*4);
    int*   partial  = (int*)alloc((size_t)SCAN_NB*4);
    int2*  cs       = (int2*)alloc((size_t)NEDGE*8);
    unsigned short* Xbuf1  = (unsigned short*)alloc((size_t)N_ENT*PITCH*2);
    unsigned short* Pbuf1  = (unsigned short*)alloc((size_t)N_ENT*PITCH*2);
    unsigned short* Xbuf2  = (unsigned short*)alloc((size_t)N_ENT*PITCH*2);
    unsigned short* Pbuf2  = (unsigned short*)alloc((size_t)N_ENT*PITCH*2);
    unsigned short* relavg = (unsigned short*)alloc((size_t)N_ENT*PITCH*2);
    unsigned short* relb   = (unsigned short*)alloc((size_t)RELB_ELEMS*2);
    unsigned short* Bp1    = (unsigned short*)alloc((size_t)BP_ELEMS*2);
    unsigned short* Bp2    = (unsigned short*)alloc((size_t)BP_ELEMS*2);
    unsigned short* qb     = (unsigned short*)alloc((size_t)BDIM*PITCH*2);
    float* gate   = (float*)alloc((size_t)N_ENT*4);
    float* bnpart = (float*)alloc((size_t)BN_NB*6*4);
    float* bnp    = (float*)alloc(64);
    unsigned short* hfb = Xbuf1;   // gemm2 output reuses Xbuf1 (dead after spmm1)

    const int EB = (NEDGE + 255)/256;
    const int INIT_NB = 98 + 101 + 91 + 91 + N_ENT/4;

    init_k<<<INIT_NB,256,0,stream>>>(ent, rel, Wn1, Wl1, Wn2, Wl2, deg, relb, Bp1, Bp2, Xbuf1);
    hist_k<<<EB,256,0,stream>>>(dst, deg);
    scan_part_k<<<SCAN_NB,256,0,stream>>>(deg, partial);
    scan_mid_k<<<1,128,0,stream>>>(partial);
    scan_fin_k<<<SCAN_NB,256,0,stream>>>(deg, partial, row_off, fill_pos);
    fill_k<<<EB,256,0,stream>>>(src, dst, etype, fill_pos, cs);
    gate_k<<<N_ENT/4,256,0,stream>>>(gtheta, gw, gb, gate);

    const int NWB = N_ENT/4;             // spmm: 4 waves/block, 1 node/wave
    const int GTB = (N_ENT + 127)/128;   // gemm: 128-row tiles

    // layer 1 (emits relavg, reused by layer 2)
    spmm1_k<<<NWB,256,0,stream>>>(Xbuf1, Pbuf1, relb, cs, row_off, relavg);
    gemm_layer_mfma_k<1><<<GTB,256,0,stream>>>(Pbuf1, Xbuf1, Bp1, Xbuf2, nullptr, nullptr);

    // layer 2 (+ gate blend) -> hfb (= Xbuf1)
    spmm2_k<<<NWB,256,0,stream>>>(Xbuf2, Pbuf2, relavg, cs, row_off);
    gemm_layer_mfma_k<2><<<GTB,256,0,stream>>>(Pbuf2, Xbuf2, Bp2, hfb, gate, ent);

    // ConvE head
    bn_part_k<<<BN_NB,256,0,stream>>>(hfb, rel, freq, s_idx, r_idx, bnpart);
    bn_fin_k<<<1,64,0,stream>>>(bnpart, bnp);
    qt_k<<<(BDIM*PITCH+255)/256,256,0,stream>>>(hfb, rel, freq, s_idx, r_idx, gamma, beta, convw, convb, bnp, qb);

    // scores
    scores_mfma_k<<<(N_ENT+63)/64,256,0,stream>>>(hfb, qb, out);

    (void)in_sizes; (void)n_in; (void)out_size; (void)ws_size;
}

// Round 7
// 563.633 us; speedup vs baseline: 3.6514x; 1.0189x over previous
//
#include <hip/hip_runtime.h>

#define N_ENT 100000
#define HDIM  200
#define NEDGE 1000000
#define BDIM  512
#define PITCH 224            // bf16 row pitch (elems); 448B, 64B-aligned
#define PITCH8 256           // fp8 row pitch (bytes); 64B-aligned
#define NSEG  28             // PITCH/8
#define NF    13             // 13 x 16 = 208 output cols
#define SCAN_TILE 1024
#define SCAN_NB   ((N_ENT + SCAN_TILE - 1)/SCAN_TILE)   // 98
#define BN_NB 32
#define RELB_ELEMS (460*PITCH)
#define BP_ELEMS   (14*NF*64*8)   // 93184

typedef short  short8v __attribute__((ext_vector_type(8)));
typedef float  float4v __attribute__((ext_vector_type(4)));
typedef float  float2v __attribute__((ext_vector_type(2)));

__device__ __forceinline__ float rrelu_f(float v){
    const float slope = (1.0f/8.0f + 1.0f/3.0f)*0.5f;
    return v >= 0.f ? v : v*slope;
}
__device__ __forceinline__ unsigned short f2bf(float f){
    unsigned int x = __float_as_uint(f);
    unsigned int r = (x + 0x7fffu + ((x >> 16) & 1u)) >> 16;
    return (unsigned short)r;
}
__device__ __forceinline__ float bf2f(unsigned short u){
    return __uint_as_float(((unsigned int)u) << 16);
}
__device__ __forceinline__ unsigned int pack_fp8x4(float a, float b, float c, float d){
    unsigned int w = 0;
    w = __builtin_amdgcn_cvt_pk_fp8_f32(a, b, w, false);
    w = __builtin_amdgcn_cvt_pk_fp8_f32(c, d, w, true);
    return w;
}

// ---- fused init: deg=0 | relb | Bp1 | Bp2 | Xbuf1/X8_1=ent | gate -------
__device__ __forceinline__ void pack_b(int b, const float* __restrict__ Wn,
        const float* __restrict__ Wl, unsigned short* __restrict__ Bp){
    int i = b*1024 + threadIdx.x*4;
    #pragma unroll
    for (int k=0;k<4;k++){
        int idx = i+k;
        if (idx < BP_ELEMS){
            int j = idx & 7, l = (idx >> 3) & 63, rest = idx >> 9;
            int f = rest % NF, ks = rest / NF;
            int kk = ks*32 + ((l >> 4) << 3) + j;
            int c  = f*16 + (l & 15);
            float v = 0.f;
            if (c < HDIM){
                if (kk < 200)                   v = Wn[(size_t)kk*HDIM + c];
                else if (kk >= 224 && kk < 424) v = Wl[(size_t)(kk-224)*HDIM + c];
            }
            Bp[idx] = f2bf(v);
        }
    }
}

__global__ __launch_bounds__(256) void init_k(const float* __restrict__ ent,
        const float* __restrict__ rel,
        const float* __restrict__ Wn1, const float* __restrict__ Wl1,
        const float* __restrict__ Wn2, const float* __restrict__ Wl2,
        const float* __restrict__ gtheta, const float* __restrict__ gw,
        const float* __restrict__ gb,
        int* __restrict__ deg, unsigned short* __restrict__ relb,
        unsigned short* __restrict__ Bp1, unsigned short* __restrict__ Bp2,
        unsigned short* __restrict__ Xbuf1, unsigned char* __restrict__ X8_1,
        float* __restrict__ gate){
    int b = blockIdx.x;
    if (b < 98){
        int i = b*1024 + threadIdx.x*4;
        if (i+3 < N_ENT) *(int4*)(deg+i) = make_int4(0,0,0,0);
        else { for (int k=0;k<4;k++) if (i+k < N_ENT) deg[i+k]=0; }
        return;
    }
    b -= 98;
    if (b < 101){
        int i = b*1024 + threadIdx.x*4;
        #pragma unroll
        for (int k=0;k<4;k++){
            int idx = i+k;
            if (idx < RELB_ELEMS){
                int r = idx / PITCH, c = idx - r*PITCH;
                relb[idx] = (c < HDIM) ? f2bf(rel[(size_t)r*HDIM + c]) : 0;
            }
        }
        return;
    }
    b -= 101;
    if (b < 91){ pack_b(b, Wn1, Wl1, Bp1); return; }
    b -= 91;
    if (b < 91){ pack_b(b, Wn2, Wl2, Bp2); return; }
    b -= 91;
    int w = threadIdx.x >> 6, l = threadIdx.x & 63;
    if (b < N_ENT/4){
        // Xbuf1 (bf16) + X8_1 (fp8), 4 rows/block
        if (l >= 56) return;
        int n = b*4 + w;
        int el = 4*l;
        ushort4 o;
        float4 v = make_float4(0.f,0.f,0.f,0.f);
        if (el < HDIM) v = *(const float4*)(ent + (size_t)n*HDIM + el);
        o.x=f2bf(v.x); o.y=f2bf(v.y); o.z=f2bf(v.z); o.w=f2bf(v.w);
        *(ushort4*)(Xbuf1 + (size_t)n*PITCH + el) = o;
        *(unsigned int*)(X8_1 + (size_t)n*PITCH8 + el) = pack_fp8x4(v.x,v.y,v.z,v.w);
        return;
    }
    b -= N_ENT/4;
    {   // gate: 4 nodes/block, one wave each
        int n = b*4 + w;
        const float* t = gtheta + (size_t)n*HDIM;
        float s = t[l]*gw[l] + t[64+l]*gw[64+l] + t[128+l]*gw[128+l];
        if (l<8) s += t[192+l]*gw[192+l];
        #pragma unroll
        for (int off=32; off>=1; off>>=1) s += __shfl_xor(s, off);
        if (l==0) gate[n] = 1.f/(1.f + expf(-(s + gb[0])));
    }
}

// ---- CSR build ----------------------------------------------------------
__global__ void hist_k(const int* __restrict__ dst, int* __restrict__ deg){
    int e = blockIdx.x*blockDim.x + threadIdx.x;
    if (e < NEDGE) atomicAdd(&deg[dst[e]], 1);
}

__global__ __launch_bounds__(256) void scan_part_k(const int* __restrict__ deg, int* __restrict__ partial){
    int t = threadIdx.x;
    int base = blockIdx.x*SCAN_TILE + t*4;
    int s = 0;
    if (base + 3 < N_ENT){
        int4 v = *(const int4*)(deg + base);
        s = v.x + v.y + v.z + v.w;
    } else {
        for (int i=0;i<4;i++) if (base+i < N_ENT) s += deg[base+i];
    }
    #pragma unroll
    for (int off=32; off>=1; off>>=1) s += __shfl_xor(s, off);
    __shared__ int ws[4];
    if ((t&63)==0) ws[t>>6] = s;
    __syncthreads();
    if (t==0) partial[blockIdx.x] = ws[0]+ws[1]+ws[2]+ws[3];
}

__global__ void scan_mid_k(int* __restrict__ partial){
    __shared__ int sh[128];
    int t = threadIdx.x;
    int v = (t < SCAN_NB) ? partial[t] : 0;
    sh[t] = v;
    __syncthreads();
    for (int off=1; off<128; off<<=1){
        int u = (t>=off) ? sh[t-off] : 0;
        __syncthreads();
        sh[t] += u;
        __syncthreads();
    }
    if (t < SCAN_NB) partial[t] = sh[t] - v;   // exclusive
}

__global__ __launch_bounds__(256) void scan_fin_k(const int* __restrict__ deg, const int* __restrict__ partial,
        int* __restrict__ row_off, int* __restrict__ fill_pos){
    int t = threadIdx.x;
    int lane = t & 63;
    int base = blockIdx.x*SCAN_TILE + t*4;
    int v0=0,v1=0,v2=0,v3=0;
    if (base+3 < N_ENT){
        int4 v = *(const int4*)(deg + base);
        v0=v.x; v1=v.y; v2=v.z; v3=v.w;
    } else {
        if (base   < N_ENT) v0 = deg[base];
        if (base+1 < N_ENT) v1 = deg[base+1];
        if (base+2 < N_ENT) v2 = deg[base+2];
        if (base+3 < N_ENT) v3 = deg[base+3];
    }
    int s = v0+v1+v2+v3;
    int inc = s;
    #pragma unroll
    for (int off=1; off<64; off<<=1){
        int u = __shfl_up(inc, off);
        if (lane >= off) inc += u;
    }
    __shared__ int wsum[4];
    if (lane==63) wsum[t>>6] = inc;
    __syncthreads();
    int w = t>>6;
    int woff = 0;
    for (int i=0;i<w;i++) woff += wsum[i];
    int exc = partial[blockIdx.x] + woff + inc - s;
    int r0 = exc, r1 = exc+v0, r2 = exc+v0+v1, r3 = exc+v0+v1+v2;
    if (base+3 < N_ENT){
        *(int4*)(row_off+base)  = make_int4(r0,r1,r2,r3);
        *(int4*)(fill_pos+base) = make_int4(r0,r1,r2,r3);
    } else {
        if (base   < N_ENT){ row_off[base]  =r0; fill_pos[base]  =r0; }
        if (base+1 < N_ENT){ row_off[base+1]=r1; fill_pos[base+1]=r1; }
        if (base+2 < N_ENT){ row_off[base+2]=r2; fill_pos[base+2]=r2; }
        if (base+3 < N_ENT){ row_off[base+3]=r3; fill_pos[base+3]=r3; }
    }
    if (blockIdx.x==0 && t==0) row_off[N_ENT] = NEDGE;
}

__global__ void fill_k(const int* __restrict__ src, const int* __restrict__ dst, const int* __restrict__ et,
                       int* __restrict__ fill_pos, int2* __restrict__ cs){
    int e = blockIdx.x*blockDim.x + threadIdx.x;
    if (e < NEDGE){
        int p = atomicAdd(&fill_pos[dst[e]], 1);
        cs[p] = make_int2(src[e], et[e]);
    }
}

// ---- spmm layer 1: fp8 X-gather + bf16 rel-gather, write P1 and relavg --
__global__ __launch_bounds__(256) void spmm1_k(const unsigned char* __restrict__ X8,
        unsigned short* __restrict__ P,
        const unsigned short* __restrict__ relb,
        const int2* __restrict__ cs,
        const int* __restrict__ row_off,
        unsigned short* __restrict__ relavg){
    int wv = (blockIdx.x*256 + threadIdx.x) >> 6;
    int l = threadIdx.x & 63;
    if (l >= 56) return;
    int beg = row_off[wv], end = row_off[wv+1];
    const int el = 4*l;
    float x0=0.f,x1=0.f,x2=0.f,x3=0.f;
    float r0=0.f,r1=0.f,r2=0.f,r3=0.f;
    int e = beg;
    for (; e+4 <= end; e+=4){
        int2 c0 = cs[e], c1 = cs[e+1], c2 = cs[e+2], c3 = cs[e+3];
        unsigned int ua = *(const unsigned int*)(X8 + (size_t)c0.x*PITCH8 + el);
        unsigned int ub = *(const unsigned int*)(X8 + (size_t)c1.x*PITCH8 + el);
        unsigned int uc = *(const unsigned int*)(X8 + (size_t)c2.x*PITCH8 + el);
        unsigned int ud = *(const unsigned int*)(X8 + (size_t)c3.x*PITCH8 + el);
        ushort4 ra = *(const ushort4*)(relb + (size_t)c0.y*PITCH + el);
        ushort4 rb = *(const ushort4*)(relb + (size_t)c1.y*PITCH + el);
        ushort4 rc = *(const ushort4*)(relb + (size_t)c2.y*PITCH + el);
        ushort4 rd = *(const ushort4*)(relb + (size_t)c3.y*PITCH + el);
        float2v alo = __builtin_amdgcn_cvt_pk_f32_fp8((int)ua, false);
        float2v ahi = __builtin_amdgcn_cvt_pk_f32_fp8((int)ua, true);
        float2v blo = __builtin_amdgcn_cvt_pk_f32_fp8((int)ub, false);
        float2v bhi = __builtin_amdgcn_cvt_pk_f32_fp8((int)ub, true);
        float2v clo = __builtin_amdgcn_cvt_pk_f32_fp8((int)uc, false);
        float2v chi = __builtin_amdgcn_cvt_pk_f32_fp8((int)uc, true);
        float2v dlo = __builtin_amdgcn_cvt_pk_f32_fp8((int)ud, false);
        float2v dhi = __builtin_amdgcn_cvt_pk_f32_fp8((int)ud, true);
        x0 += alo[0]+blo[0]+clo[0]+dlo[0];
        x1 += alo[1]+blo[1]+clo[1]+dlo[1];
        x2 += ahi[0]+bhi[0]+chi[0]+dhi[0];
        x3 += ahi[1]+bhi[1]+chi[1]+dhi[1];
        r0 += bf2f(ra.x)+bf2f(rb.x)+bf2f(rc.x)+bf2f(rd.x);
        r1 += bf2f(ra.y)+bf2f(rb.y)+bf2f(rc.y)+bf2f(rd.y);
        r2 += bf2f(ra.z)+bf2f(rb.z)+bf2f(rc.z)+bf2f(rd.z);
        r3 += bf2f(ra.w)+bf2f(rb.w)+bf2f(rc.w)+bf2f(rd.w);
    }
    for (; e<end; e++){
        int2 c0 = cs[e];
        unsigned int ua = *(const unsigned int*)(X8 + (size_t)c0.x*PITCH8 + el);
        ushort4 ra = *(const ushort4*)(relb + (size_t)c0.y*PITCH + el);
        float2v alo = __builtin_amdgcn_cvt_pk_f32_fp8((int)ua, false);
        float2v ahi = __builtin_amdgcn_cvt_pk_f32_fp8((int)ua, true);
        x0 += alo[0]; x1 += alo[1]; x2 += ahi[0]; x3 += ahi[1];
        r0 += bf2f(ra.x); r1 += bf2f(ra.y); r2 += bf2f(ra.z); r3 += bf2f(ra.w);
    }
    float id = 1.f / fmaxf((float)(end-beg), 1.f);
    float g0 = r0*id, g1 = r1*id, g2 = r2*id, g3 = r3*id;
    ushort4 rv; rv.x=f2bf(g0); rv.y=f2bf(g1); rv.z=f2bf(g2); rv.w=f2bf(g3);
    *(ushort4*)(relavg + (size_t)wv*PITCH + el) = rv;
    ushort4 o;
    o.x=f2bf(x0*id+g0); o.y=f2bf(x1*id+g1); o.z=f2bf(x2*id+g2); o.w=f2bf(x3*id+g3);
    *(ushort4*)(P + (size_t)wv*PITCH + el) = o;
}

// ---- spmm layer 2: fp8 X-gather + stream relavg, write P2 ---------------
__global__ __launch_bounds__(256) void spmm2_k(const unsigned char* __restrict__ X8,
        unsigned short* __restrict__ P,
        const unsigned short* __restrict__ relavg,
        const int2* __restrict__ cs,
        const int* __restrict__ row_off){
    int wv = (blockIdx.x*256 + threadIdx.x) >> 6;
    int l = threadIdx.x & 63;
    if (l >= 56) return;
    int beg = row_off[wv], end = row_off[wv+1];
    const int el = 4*l;
    ushort4 rv = *(const ushort4*)(relavg + (size_t)wv*PITCH + el);
    float x0=0.f,x1=0.f,x2=0.f,x3=0.f;
    int e = beg;
    for (; e+4 <= end; e+=4){
        int2 c0 = cs[e], c1 = cs[e+1], c2 = cs[e+2], c3 = cs[e+3];
        unsigned int ua = *(const unsigned int*)(X8 + (size_t)c0.x*PITCH8 + el);
        unsigned int ub = *(const unsigned int*)(X8 + (size_t)c1.x*PITCH8 + el);
        unsigned int uc = *(const unsigned int*)(X8 + (size_t)c2.x*PITCH8 + el);
        unsigned int ud = *(const unsigned int*)(X8 + (size_t)c3.x*PITCH8 + el);
        float2v alo = __builtin_amdgcn_cvt_pk_f32_fp8((int)ua, false);
        float2v ahi = __builtin_amdgcn_cvt_pk_f32_fp8((int)ua, true);
        float2v blo = __builtin_amdgcn_cvt_pk_f32_fp8((int)ub, false);
        float2v bhi = __builtin_amdgcn_cvt_pk_f32_fp8((int)ub, true);
        float2v clo = __builtin_amdgcn_cvt_pk_f32_fp8((int)uc, false);
        float2v chi = __builtin_amdgcn_cvt_pk_f32_fp8((int)uc, true);
        float2v dlo = __builtin_amdgcn_cvt_pk_f32_fp8((int)ud, false);
        float2v dhi = __builtin_amdgcn_cvt_pk_f32_fp8((int)ud, true);
        x0 += alo[0]+blo[0]+clo[0]+dlo[0];
        x1 += alo[1]+blo[1]+clo[1]+dlo[1];
        x2 += ahi[0]+bhi[0]+chi[0]+dhi[0];
        x3 += ahi[1]+bhi[1]+chi[1]+dhi[1];
    }
    for (; e<end; e++){
        int2 c0 = cs[e];
        unsigned int ua = *(const unsigned int*)(X8 + (size_t)c0.x*PITCH8 + el);
        float2v alo = __builtin_amdgcn_cvt_pk_f32_fp8((int)ua, false);
        float2v ahi = __builtin_amdgcn_cvt_pk_f32_fp8((int)ua, true);
        x0 += alo[0]; x1 += alo[1]; x2 += ahi[0]; x3 += ahi[1];
    }
    float id = 1.f / fmaxf((float)(end-beg), 1.f);
    ushort4 o;
    o.x=f2bf(x0*id+bf2f(rv.x)); o.y=f2bf(x1*id+bf2f(rv.y));
    o.z=f2bf(x2*id+bf2f(rv.z)); o.w=f2bf(x3*id+bf2f(rv.w));
    *(ushort4*)(P + (size_t)wv*PITCH + el) = o;
}

// ---- layer GEMM via MFMA: Out = act([P|X] @ [Wn;Wl]), K=448 --------------
// 128 rows/block, 32 rows/wave. Epilogue via LDS, 16B stores, pads zeroed.
// EPI==1 additionally writes the fp8 gather table for the next spmm.
template<int EPI>
__global__ __launch_bounds__(256,2) void gemm_layer_mfma_k(
        const unsigned short* __restrict__ Pb,
        const unsigned short* __restrict__ Xb,
        const unsigned short* __restrict__ Bpack,
        unsigned short* __restrict__ OutB,
        unsigned char* __restrict__ X8out,
        const float* __restrict__ gate, const float* __restrict__ ent){
    __shared__ unsigned short OutS[128*PITCH];
    const int tid = threadIdx.x;
    const int l   = tid & 63;
    const int w   = tid >> 6;
    const int n0  = blockIdx.x * 128;
    const int lr  = l & 15;
    const int lg  = l >> 4;
    int r0 = n0 + w*32 + lr;
    int r1 = r0 + 16;
    int c0 = r0 < N_ENT ? r0 : N_ENT-1;
    int c1 = r1 < N_ENT ? r1 : N_ENT-1;
    float4v acc[2][NF];
    #pragma unroll
    for (int f=0; f<NF; f++){
        acc[0][f] = (float4v){0.f,0.f,0.f,0.f};
        acc[1][f] = (float4v){0.f,0.f,0.f,0.f};
    }
    #pragma unroll 1
    for (int sec=0; sec<2; sec++){
        const unsigned short* base = sec ? Xb : Pb;
        const unsigned short* a0p = base + (size_t)c0*PITCH + lg*8;
        const unsigned short* a1p = base + (size_t)c1*PITCH + lg*8;
        const unsigned short* bp0 = Bpack + (((size_t)(sec*7*NF))*64 + l)*8;
        for (int ks=0; ks<7; ks++){
            short8v a0 = *(const short8v*)(a0p + ks*32);
            short8v a1 = *(const short8v*)(a1p + ks*32);
            const unsigned short* bp = bp0 + (size_t)ks*NF*512;
            #pragma unroll
            for (int f=0; f<NF; f++){
                short8v b = *(const short8v*)(bp + (size_t)f*512);
                acc[0][f] = __builtin_amdgcn_mfma_f32_16x16x32_bf16(a0, b, acc[0][f], 0, 0, 0);
                acc[1][f] = __builtin_amdgcn_mfma_f32_16x16x32_bf16(a1, b, acc[1][f], 0, 0, 0);
            }
        }
    }
    #pragma unroll
    for (int f=0; f<NF; f++){
        int c = f*16 + lr;
        if (c < HDIM){
            #pragma unroll
            for (int j=0; j<4; j++){
                OutS[(w*32 + lg*4 + j)*PITCH + c]      = f2bf(rrelu_f(acc[0][f][j]));
                OutS[(w*32 + 16 + lg*4 + j)*PITCH + c] = f2bf(rrelu_f(acc[1][f][j]));
            }
        }
    }
    __syncthreads();
    for (int i = tid; i < 128*NSEG; i += 256){
        int r = i/NSEG, seg = i - r*NSEG;
        int n = n0 + r;
        if (n >= N_ENT) continue;
        short8v o;
        uint2 p8 = make_uint2(0u, 0u);
        if (seg >= 25){
            #pragma unroll
            for (int j=0;j<8;j++) o[j]=0;
        } else {
            short8v v = *(const short8v*)(&OutS[r*PITCH + seg*8]);
            if (EPI == 2){
                float g = gate[n];
                const float4* ef = (const float4*)(ent + (size_t)n*HDIM + seg*8);
                float4 e0 = ef[0], e1 = ef[1];
                float ev[8] = {e0.x,e0.y,e0.z,e0.w,e1.x,e1.y,e1.z,e1.w};
                #pragma unroll
                for (int j=0; j<8; j++){
                    float x = g*bf2f((unsigned short)v[j]) + (1.f-g)*ev[j];
                    o[j] = (short)f2bf(x);
                }
            } else {
                o = v;
                float f0=bf2f((unsigned short)v[0]), f1=bf2f((unsigned short)v[1]);
                float f2=bf2f((unsigned short)v[2]), f3=bf2f((unsigned short)v[3]);
                float f4=bf2f((unsigned short)v[4]), f5=bf2f((unsigned short)v[5]);
                float f6=bf2f((unsigned short)v[6]), f7=bf2f((unsigned short)v[7]);
                p8.x = pack_fp8x4(f0,f1,f2,f3);
                p8.y = pack_fp8x4(f4,f5,f6,f7);
            }
        }
        *(short8v*)(OutB + (size_t)n*PITCH + seg*8) = o;
        if (EPI == 1) *(uint2*)(X8out + (size_t)n*PITCH8 + seg*8) = p8;
    }
}

// ---- BN stats: stage 1 (32-block deterministic partial sums) ------------
__global__ __launch_bounds__(256) void bn_part_k(const unsigned short* __restrict__ hfb,
        const float* __restrict__ rel, const float* __restrict__ freq,
        const int* __restrict__ s_idx, const int* __restrict__ r_idx,
        float* __restrict__ bnpart){
    int t = threadIdx.x;
    float acc[6] = {0,0,0,0,0,0};
    for (int i = blockIdx.x*256 + t; i < BDIM*HDIM; i += BN_NB*256){
        int b = i/HDIM, h = i - b*HDIM;
        float e = bf2f(hfb[(size_t)s_idx[b]*PITCH + h]);
        float r = rel[(size_t)r_idx[b]*HDIM + h];
        float f = freq[i];
        acc[0]+=e; acc[1]+=e*e; acc[2]+=r; acc[3]+=r*r; acc[4]+=f; acc[5]+=f*f;
    }
    __shared__ float red[4][6];
    #pragma unroll
    for (int c=0;c<6;c++){
        float s = acc[c];
        #pragma unroll
        for (int off=32; off>=1; off>>=1) s += __shfl_xor(s, off);
        if ((t&63)==0) red[t>>6][c] = s;
    }
    __syncthreads();
    if (t==0){
        #pragma unroll
        for (int c=0;c<6;c++)
            bnpart[blockIdx.x*6+c] = red[0][c]+red[1][c]+red[2][c]+red[3][c];
    }
}

// ---- q row-major bf16 [512][PITCH] (bn_fin folded in), pads zeroed ------
__global__ __launch_bounds__(256) void qt_k(const unsigned short* __restrict__ hfb,
        const float* __restrict__ rel,
        const float* __restrict__ freq, const int* __restrict__ s_idx, const int* __restrict__ r_idx,
        const float* __restrict__ gamma, const float* __restrict__ beta,
        const float* __restrict__ convw, const float* __restrict__ convb,
        const float* __restrict__ bnpart, unsigned short* __restrict__ qb){
    __shared__ float bnp_s[6];
    if (threadIdx.x < 6){
        float s = 0.f;
        for (int b=0;b<BN_NB;b++) s += bnpart[b*6 + threadIdx.x];
        bnp_s[threadIdx.x] = s;
    }
    __syncthreads();
    const float inv = 1.f/(float)(BDIM*HDIM);
    float m0 = bnp_s[0]*inv, m1 = bnp_s[2]*inv, m2 = bnp_s[4]*inv;
    float i0 = rsqrtf(bnp_s[1]*inv - m0*m0 + 1e-5f);
    float i1 = rsqrtf(bnp_s[3]*inv - m1*m1 + 1e-5f);
    float i2 = rsqrtf(bnp_s[5]*inv - m2*m2 + 1e-5f);
    int i = blockIdx.x*blockDim.x + threadIdx.x;
    if (i >= BDIM*PITCH) return;
    int b = i/PITCH, h = i - b*PITCH;
    if (h >= HDIM){ qb[i] = 0; return; }
    float x0 = bf2f(hfb[(size_t)s_idx[b]*PITCH + h]);
    float x1 = rel[(size_t)r_idx[b]*HDIM + h];
    float x2 = freq[(size_t)b*HDIM + h];
    float v0 = fmaxf((x0-m0)*i0*gamma[0] + beta[0], 0.f);
    float v1 = fmaxf((x1-m1)*i1*gamma[1] + beta[1], 0.f);
    float v2 = fmaxf((x2-m2)*i2*gamma[2] + beta[2], 0.f);
    float q = v0*convw[0] + v1*convw[1] + v2*convw[2] + convb[0];
    qb[(size_t)b*PITCH + h] = f2bf(q);
}

// ---- scores[b][n] = q[b] . hf[n] via MFMA, 64-row n-tiles ---------------
__global__ __launch_bounds__(256,2) void scores_mfma_k(
        const unsigned short* __restrict__ hfb,
        const unsigned short* __restrict__ qb,
        float* __restrict__ out){
    const int tid = threadIdx.x;
    const int l   = tid & 63;
    const int w   = tid >> 6;
    const int lr  = l & 15;
    const int lg  = l >> 4;
    const int n0  = blockIdx.x * 64;
    float4v acc[8][4];
    #pragma unroll
    for (int bf=0; bf<8; bf++)
        #pragma unroll
        for (int nf=0; nf<4; nf++) acc[bf][nf] = (float4v){0,0,0,0};
    const unsigned short* hptr[4];
    #pragma unroll
    for (int nf=0; nf<4; nf++){
        int n = n0 + nf*16 + lr;
        if (n >= N_ENT) n = N_ENT-1;
        hptr[nf] = hfb + (size_t)n*PITCH + lg*8;
    }
    const unsigned short* qrow = qb + (size_t)(w*128 + lr)*PITCH + lg*8;
    for (int ks=0; ks<7; ks++){
        short8v hv[4];
        #pragma unroll
        for (int nf=0; nf<4; nf++) hv[nf] = *(const short8v*)(hptr[nf] + ks*32);
        #pragma unroll
        for (int bf=0; bf<8; bf++){
            short8v q = *(const short8v*)(qrow + (size_t)bf*16*PITCH + ks*32);
            #pragma unroll
            for (int nf=0; nf<4; nf++)
                acc[bf][nf] = __builtin_amdgcn_mfma_f32_16x16x32_bf16(q, hv[nf], acc[bf][nf], 0, 0, 0);
        }
    }
    #pragma unroll
    for (int bf=0; bf<8; bf++){
        int b = w*128 + bf*16 + lg*4;
        #pragma unroll
        for (int nf=0; nf<4; nf++){
            int n = n0 + nf*16 + lr;
            if (n >= N_ENT) continue;
            #pragma unroll
            for (int j=0; j<4; j++){
                out[(size_t)(b+j)*N_ENT + n] = acc[bf][nf][j];
            }
        }
    }
}

extern "C" void kernel_launch(void* const* d_in, const int* in_sizes, int n_in,
                              void* d_out, int out_size, void* d_ws, size_t ws_size,
                              hipStream_t stream) {
    const float* ent    = (const float*)d_in[0];
    const float* rel    = (const float*)d_in[1];
    const float* Wn1    = (const float*)d_in[2];
    const float* Wl1    = (const float*)d_in[3];
    const float* Wn2    = (const float*)d_in[4];
    const float* Wl2    = (const float*)d_in[5];
    const float* gtheta = (const float*)d_in[6];
    const float* gw     = (const float*)d_in[7];
    const float* gb     = (const float*)d_in[8];
    const float* gamma  = (const float*)d_in[9];
    const float* beta   = (const float*)d_in[10];
    const float* convw  = (const float*)d_in[11];
    const float* convb  = (const float*)d_in[12];
    const float* freq   = (const float*)d_in[13];
    const int*   src    = (const int*)d_in[14];
    const int*   dst    = (const int*)d_in[15];
    const int*   etype  = (const int*)d_in[16];
    const int*   s_idx  = (const int*)d_in[17];
    const int*   r_idx  = (const int*)d_in[18];
    float* out = (float*)d_out;

    char* ws = (char*)d_ws;
    size_t off = 0;
    auto alloc = [&](size_t bytes)->char*{
        char* p = ws + off;
        off += (bytes + 511) & ~(size_t)511;
        return p;
    };
    int*   deg      = (int*)alloc((size_t)N_ENT*4);
    int*   row_off  = (int*)alloc((size_t)(N_ENT+1)*4);
    int*   fill_pos = (int*)alloc((size_t)N_ENT*4);
    int*   partial  = (int*)alloc((size_t)SCAN_NB*4);
    int2*  cs       = (int2*)alloc((size_t)NEDGE*8);
    unsigned short* Xbuf1  = (unsigned short*)alloc((size_t)N_ENT*PITCH*2);
    unsigned short* Xbuf2  = (unsigned short*)alloc((size_t)N_ENT*PITCH*2);
    unsigned short* Pbuf   = (unsigned short*)alloc((size_t)N_ENT*PITCH*2);   // shared P1/P2
    unsigned short* relavg = (unsigned short*)alloc((size_t)N_ENT*PITCH*2);
    unsigned char*  X8_1   = (unsigned char*)alloc((size_t)N_ENT*PITCH8);
    unsigned char*  X8_2   = (unsigned char*)alloc((size_t)N_ENT*PITCH8);
    unsigned short* relb   = (unsigned short*)alloc((size_t)RELB_ELEMS*2);
    unsigned short* Bp1    = (unsigned short*)alloc((size_t)BP_ELEMS*2);
    unsigned short* Bp2    = (unsigned short*)alloc((size_t)BP_ELEMS*2);
    unsigned short* qb     = (unsigned short*)alloc((size_t)BDIM*PITCH*2);
    float* gate   = (float*)alloc((size_t)N_ENT*4);
    float* bnpart = (float*)alloc((size_t)BN_NB*6*4);
    unsigned short* hfb = Xbuf1;   // gemm2 output reuses Xbuf1 (dead after gemm1)

    const int EB = (NEDGE + 255)/256;
    const int INIT_NB = 98 + 101 + 91 + 91 + N_ENT/4 + N_ENT/4;

    init_k<<<INIT_NB,256,0,stream>>>(ent, rel, Wn1, Wl1, Wn2, Wl2, gtheta, gw, gb,
                                     deg, relb, Bp1, Bp2, Xbuf1, X8_1, gate);
    hist_k<<<EB,256,0,stream>>>(dst, deg);
    scan_part_k<<<SCAN_NB,256,0,stream>>>(deg, partial);
    scan_mid_k<<<1,128,0,stream>>>(partial);
    scan_fin_k<<<SCAN_NB,256,0,stream>>>(deg, partial, row_off, fill_pos);
    fill_k<<<EB,256,0,stream>>>(src, dst, etype, fill_pos, cs);

    const int NWB = N_ENT/4;             // spmm: 4 waves/block, 1 node/wave
    const int GTB = (N_ENT + 127)/128;   // gemm: 128-row tiles

    // layer 1 (emits relavg, reused by layer 2); gemm1 emits h1 bf16 + fp8
    spmm1_k<<<NWB,256,0,stream>>>(X8_1, Pbuf, relb, cs, row_off, relavg);
    gemm_layer_mfma_k<1><<<GTB,256,0,stream>>>(Pbuf, Xbuf1, Bp1, Xbuf2, X8_2, nullptr, nullptr);

    // layer 2 (+ gate blend) -> hfb (= Xbuf1)
    spmm2_k<<<NWB,256,0,stream>>>(X8_2, Pbuf, relavg, cs, row_off);
    gemm_layer_mfma_k<2><<<GTB,256,0,stream>>>(Pbuf, Xbuf2, Bp2, hfb, nullptr, gate, ent);

    // ConvE head
    bn_part_k<<<BN_NB,256,0,stream>>>(hfb, rel, freq, s_idx, r_idx, bnpart);
    qt_k<<<(BDIM*PITCH+255)/256,256,0,stream>>>(hfb, rel, freq, s_idx, r_idx, gamma, beta, convw, convb, bnpart, qb);

    // scores
    scores_mfma_k<<<(N_ENT+63)/64,256,0,stream>>>(hfb, qb, out);

    (void)in_sizes; (void)n_in; (void)out_size; (void)ws_size;
}